// Round 13
// baseline (2108.566 us; speedup 1.0000x reference)
//
#include <hip/hip_runtime.h>
#include <math.h>

// ---------------- problem constants ----------------
#define BATCH 16
#define L_CYC 20
#define CDL 128
#define SEQ 2560            // L_CYC * CDL
#define ENC_IN 3
#define DMODEL 512
#define DFF 2048
#define NLAYERS 2
#define TOPK 7
#define MROWS (BATCH*SEQ)   // 40960
#define SD ((size_t)BATCH * SEQ * DMODEL)   // 20,971,520
#define FFN_CHUNK 20480     // 2 chunks; 20480*2048 ushorts == SD*4 bytes exactly
#define CHUNK_D 256         // q/k column-chunk width
#define DGRP 8              // FFT channels per workgroup (proven; 4 regressed r6)
#define FFT_NT 512          // threads per FFT block (round-15 proven)

typedef short bf16x8 __attribute__((ext_vector_type(8)));
typedef float f32x4 __attribute__((ext_vector_type(4)));

// fast gelu: A&S 7.1.26 erf (|err| <= 1.5e-7), hw exp; ~14 VALU ops vs ~30 libm
__device__ __forceinline__ float gelu_f(float x) {
    float z = x * 0.70710678118654752f;
    float az = fabsf(z);
    float t = __builtin_amdgcn_rcpf(1.0f + 0.3275911f * az);
    float poly = t * (0.254829592f + t * (-0.284496736f + t * (1.421413741f
               + t * (-1.453152027f + t * 1.061405429f))));
    float e = __expf(-az * az);
    float erfv = 1.0f - poly * e;
    erfv = copysignf(erfv, z);
    return 0.5f * x * (1.0f + erfv);
}
__device__ __forceinline__ unsigned short f2bf(float f) {
    unsigned int u = __float_as_uint(f);
    u += 0x7fff + ((u >> 16) & 1);          // RNE
    return (unsigned short)(u >> 16);
}
__device__ __forceinline__ float bf2f(unsigned short h) {
    return __uint_as_float(((unsigned int)h) << 16);
}
// XCD-aware swizzle: 1-D block id p -> (row-group g, n-tile n) with all G
// n-tiles of g on the same XCD (round-robin p%8). Requires gridM % 8 == 0.
__device__ __forceinline__ void xcd_map(int p, int G, int& g, int& n) {
    int a = p >> 3;
    n = a % G;
    g = (a / G) * 8 + (p & 7);
}
// async global->LDS, 16B per lane; LDS dest is wave-uniform base + lane*16.
__device__ __forceinline__ void gload16(const unsigned short* g, unsigned short* l) {
    typedef unsigned int u32;
    __builtin_amdgcn_global_load_lds(
        (const __attribute__((address_space(1))) u32*)g,
        (__attribute__((address_space(3))) u32*)l, 16, 0, 0);
}

// -------- embed: mask + reshape + circular conv1d(k=3) + fused hi/lo split ----
// float4/ushort4 stores (r4 agg_res pattern): 2 rows/block, 4 cols/thread.
__global__ __launch_bounds__(256) void embed_kernel(
    const float* __restrict__ data, const float* __restrict__ mask,
    const float* __restrict__ Wemb, float* __restrict__ h,
    unsigned short* __restrict__ hi, unsigned short* __restrict__ lo) {
    __shared__ float xv[2][9];      // [local row][c*3 + t]
    int tid = threadIdx.x;
    size_t r0 = (size_t)blockIdx.x * 2;
    if (tid < 18) {
        int lr = tid / 9, k = tid % 9;
        int t = k / 3, c = k % 3;
        size_t r = r0 + lr;
        int s = (int)(r % SEQ);
        int b = (int)(r / SEQ);
        int u = s - 1 + t;
        if (u < 0) u += SEQ;
        if (u >= SEQ) u -= SEQ;
        int cyc = u >> 7, pos = u & 127;
        float mk = mask[b * L_CYC + cyc];
        xv[lr][c * 3 + t] = (mk == 0.f) ? 0.f
            : data[(((size_t)b * L_CYC + cyc) * ENC_IN + c) * CDL + pos];
    }
    __syncthreads();
    int lr = tid >> 7;
    int dm = (tid & 127) * 4;
    size_t idx = (r0 + lr) * DMODEL + dm;
    float a[4];
#pragma unroll
    for (int q = 0; q < 4; q++) {
        float acc = 0.f;
#pragma unroll
        for (int j = 0; j < 9; j++) acc += xv[lr][j] * Wemb[(dm + q) * 9 + j];
        a[q] = acc;
    }
    *(float4*)(h + idx) = make_float4(a[0], a[1], a[2], a[3]);
    ushort4 hv = make_ushort4(f2bf(a[0]), f2bf(a[1]), f2bf(a[2]), f2bf(a[3]));
    *(ushort4*)(hi + idx) = hv;
    ushort4 lv = make_ushort4(f2bf(a[0] - bf2f(hv.x)), f2bf(a[1] - bf2f(hv.y)),
                              f2bf(a[2] - bf2f(hv.z)), f2bf(a[3] - bf2f(hv.w)));
    *(ushort4*)(lo + idx) = lv;
}

// ---------------- transpose W[K][N] fp32 -> Wt[N][K] bf16 ----------------
__global__ __launch_bounds__(256) void transpose_bf16_kernel(
    const float* __restrict__ W, unsigned short* __restrict__ Wt, int K, int N) {
    __shared__ float t[32][33];
    int n0 = blockIdx.x * 32, k0 = blockIdx.y * 32;
    int c = threadIdx.x & 31, r = threadIdx.x >> 5;   // r: 0..7
    for (int i = 0; i < 4; i++)
        t[r + i * 8][c] = W[(size_t)(k0 + r + i * 8) * N + n0 + c];
    __syncthreads();
    for (int i = 0; i < 4; i++)
        Wt[(size_t)(n0 + r + i * 8) * K + k0 + c] = f2bf(t[c][r + i * 8]);
}

// ---- transpose 512x512 W -> STACKED hi/lo bf16: q/k interleaved per 256-chunk ----
__global__ __launch_bounds__(256) void transpose_split_stk_kernel(
    const float* __restrict__ W, unsigned short* __restrict__ WtH,
    unsigned short* __restrict__ WtL, int which) {
    __shared__ float t[32][33];
    int n0 = blockIdx.x * 32, k0 = blockIdx.y * 32;
    int c = threadIdx.x & 31, r = threadIdx.x >> 5;
    for (int i = 0; i < 4; i++)
        t[r + i * 8][c] = W[(size_t)(k0 + r + i * 8) * DMODEL + n0 + c];
    __syncthreads();
    for (int i = 0; i < 4; i++) {
        int n = n0 + r + i * 8;
        int row = (n & 255) + ((n >> 8) * 512) + which * 256;
        float v = t[c][r + i * 8];
        unsigned short h = f2bf(v);
        size_t o = (size_t)row * DMODEL + k0 + c;
        WtH[o] = h;
        WtL[o] = f2bf(v - bf2f(h));
    }
}

// ---------------- stacked bias ----------------
__global__ void stack_bias_kernel(const float* __restrict__ bq,
                                  const float* __restrict__ bk, float* __restrict__ bstk) {
    int i = blockIdx.x * 256 + threadIdx.x;     // 0..1023
    if (i >= 1024) return;
    int c = i >> 9, j = i & 511;
    bstk[i] = (j < 256) ? bq[c * 256 + j] : bk[c * 256 + (j - 256)];
}

// ---------------- Wvo = Wv @ Wo (fp32, per layer; 512 blocks) ----------------
__global__ __launch_bounds__(256) void wvo_kernel(
    const float* __restrict__ Wv, const float* __restrict__ Wo,
    float* __restrict__ Wvo) {
    __shared__ float row[DMODEL];
    int k = blockIdx.x;
    int tid = threadIdx.x;
    for (int j = tid; j < DMODEL; j += 256) row[j] = Wv[(size_t)k * DMODEL + j];
    __syncthreads();
    float a0 = 0.f, a1 = 0.f;
    for (int j = 0; j < DMODEL; j++) {
        float wv = row[j];
        a0 += wv * Wo[(size_t)j * DMODEL + tid];
        a1 += wv * Wo[(size_t)j * DMODEL + tid + 256];
    }
    Wvo[(size_t)k * DMODEL + tid] = a0;
    Wvo[(size_t)k * DMODEL + tid + 256] = a1;
}

// ---------------- cb = bv @ Wo + bo ----------------
__global__ void cbias_kernel(const float* __restrict__ bv, const float* __restrict__ Wo,
                             const float* __restrict__ bo, float* __restrict__ cb) {
    int n = blockIdx.x * 256 + threadIdx.x;
    if (n >= DMODEL) return;
    float acc = bo[n];
    for (int j = 0; j < DMODEL; j++) acc += bv[j] * Wo[(size_t)j * DMODEL + n];
    cb[n] = acc;
}

// ------ bf16 MFMA GEMM: BK=128 single-buffer 2-barrier (probe on the proven
// structure's BK axis: 32=99us, 64=85us; halves drain count again; VGPR ~80
// unchanged; 64KB LDS -> 2 blocks/CU). Swizzle for 256B rows:
// LDS[row][c16] = G[row][c16 ^ (row&7)], c16 = 16B slot in [0,16).
// Write side: gload i covers rows i*4+(lane>>4); row&7 = (lane>>4) ^ (4*(i&1)).
// Read side: slot = (kk*4 + (lane>>4)) ^ (frow&7); row&7 == frow&7 since all
// row offsets (wm*64, mi*16, wave*32) are multiples of 8.
#define BK 128
__global__ __launch_bounds__(256) void gemm_mfma_kernel(
    const unsigned short* __restrict__ A, const unsigned short* __restrict__ Wt,
    const float* __restrict__ bias, const float* res,
    void* Cout, int M, int N, int K, int act, int outMode, int gridN)
{
    __shared__ unsigned short As[128 * 128];   // 32KB
    __shared__ unsigned short Bs[128 * 128];   // 32KB
    int tid = threadIdx.x;
    int wave = tid >> 6, lane = tid & 63;
    int wm = wave & 1, wn = wave >> 1;
    int gblk, nblk;
    xcd_map(blockIdx.x, gridN, gblk, nblk);
    int bm = gblk * 128, bn = nblk * 128;

    int r4 = lane >> 4;                       // 0..3 row within 4-row gload chunk
    int c16 = lane & 15;                      // 16B col slot within 256B row
    int swcE = (c16 ^ r4) * 8;                // source col (shorts), even gload i
    int swcO = (c16 ^ (r4 ^ 4)) * 8;          // odd gload i (row&7 = r4+4)
    const unsigned short* Agb = A  + (size_t)(bm + wave * 32 + r4) * K;
    const unsigned short* Bgb = Wt + (size_t)(bn + wave * 32 + r4) * K;
    unsigned short* AsW = As + wave * 32 * 128;
    unsigned short* BsW = Bs + wave * 32 * 128;

    f32x4 acc[4][4] = {};
    int frow = lane & 15;
    int fj = lane >> 4;                       // 16B slot within 64B k-chunk
    int s7 = frow & 7;

    for (int k0 = 0; k0 < K; k0 += BK) {
        __syncthreads();                      // previous tile's reads complete
#pragma unroll
        for (int i = 0; i < 8; i++) {
            int swc = (i & 1) ? swcO : swcE;
            gload16(Agb + (size_t)(i * 4) * K + k0 + swc, AsW + i * 4 * 128);
            gload16(Bgb + (size_t)(i * 4) * K + k0 + swc, BsW + i * 4 * 128);
        }
        asm volatile("s_waitcnt vmcnt(0)" ::: "memory");
        __syncthreads();
#pragma unroll
        for (int kk = 0; kk < 4; kk++) {
            int cs = (((kk << 2) | fj) ^ s7) << 3;    // swizzled short offset
            bf16x8 af[4], bfv[4];
#pragma unroll
            for (int mi = 0; mi < 4; mi++)
                af[mi] = *(const bf16x8*)&As[(wm * 64 + mi * 16 + frow) * 128 + cs];
#pragma unroll
            for (int nj = 0; nj < 4; nj++)
                bfv[nj] = *(const bf16x8*)&Bs[(wn * 64 + nj * 16 + frow) * 128 + cs];
#pragma unroll
            for (int mi = 0; mi < 4; mi++)
#pragma unroll
                for (int nj = 0; nj < 4; nj++)
                    acc[mi][nj] = __builtin_amdgcn_mfma_f32_16x16x32_bf16(
                        af[mi], bfv[nj], acc[mi][nj], 0, 0, 0);
        }
    }

    int lrow = (lane >> 4) * 4, lcol = lane & 15;
#pragma unroll
    for (int mi = 0; mi < 4; mi++) {
        int row0 = bm + wm * 64 + mi * 16 + lrow;
#pragma unroll
        for (int nj = 0; nj < 4; nj++) {
            int col = bn + wn * 64 + nj * 16 + lcol;
            float bv = bias ? bias[col] : 0.f;
            f32x4 v = acc[mi][nj];
#pragma unroll
            for (int r = 0; r < 4; r++) {
                int row = row0 + r;
                float x = v[r] + bv;
                if (res) x += res[(size_t)row * N + col];
                if (act == 1) x = gelu_f(x);
                if (outMode == 0) ((float*)Cout)[(size_t)row * N + col] = x;
                else              ((unsigned short*)Cout)[(size_t)row * N + col] = f2bf(x);
            }
        }
    }
}

// -- split-precision MFMA GEMM for q/k (BK=32 + T2 slot swizzle both sides) ---
// Output fp32 TRANSPOSED: Ct[col*M + row]. N=512 stacked covers q&k. gridN=4.
#define QBK 32
__global__ __launch_bounds__(256) void gemm_qk_split_kernel(
    const unsigned short* __restrict__ Ahi, const unsigned short* __restrict__ Alo,
    const unsigned short* __restrict__ Whi, const unsigned short* __restrict__ Wlo,
    const float* __restrict__ bias, float* __restrict__ Ct, int M, int K, int gridN)
{
    __shared__ unsigned short AsH[128 * 32];
    __shared__ unsigned short AsL[128 * 32];
    __shared__ unsigned short BsH[128 * 32];
    __shared__ unsigned short BsL[128 * 32];
    int tid = threadIdx.x;
    int wave = tid >> 6, lane = tid & 63;
    int wm = wave & 1, wn = wave >> 1;
    int gblk, nblk;
    xcd_map(blockIdx.x, gridN, gblk, nblk);
    int bm = gblk * 128, bn = nblk * 128;

    int lrs = lane >> 2;                                    // row within 16-row chunk
    int lk  = (((lane & 3) ^ ((lane >> 3) & 3))) * 8;       // pre-swizzled source col

    f32x4 acc[4][4] = {};
    int frow = lane & 15;
    int fk = (((lane >> 4) ^ ((frow >> 1) & 3))) * 8;       // swizzled read slot

    for (int k0 = 0; k0 < K; k0 += QBK) {
        __syncthreads();
#pragma unroll
        for (int i = 0; i < 2; i++) {
            int j = wave * 2 + i;
            int row = j * 16 + lrs;
            size_t oa = (size_t)(bm + row) * K + k0 + lk;
            size_t ob = (size_t)(bn + row) * K + k0 + lk;
            gload16(Ahi + oa, AsH + j * 512);
            gload16(Alo + oa, AsL + j * 512);
            gload16(Whi + ob, BsH + j * 512);
            gload16(Wlo + ob, BsL + j * 512);
        }
        asm volatile("s_waitcnt vmcnt(0)" ::: "memory");
        __syncthreads();
        bf16x8 afh[4], afl[4], bfh[4], bfl[4];
#pragma unroll
        for (int mi = 0; mi < 4; mi++) {
            int o = (wm * 64 + mi * 16 + frow) * 32 + fk;
            afh[mi] = *(const bf16x8*)&AsH[o];
            afl[mi] = *(const bf16x8*)&AsL[o];
        }
#pragma unroll
        for (int nj = 0; nj < 4; nj++) {
            int o = (wn * 64 + nj * 16 + frow) * 32 + fk;
            bfh[nj] = *(const bf16x8*)&BsH[o];
            bfl[nj] = *(const bf16x8*)&BsL[o];
        }
#pragma unroll
        for (int mi = 0; mi < 4; mi++)
#pragma unroll
            for (int nj = 0; nj < 4; nj++) {
                acc[mi][nj] = __builtin_amdgcn_mfma_f32_16x16x32_bf16(
                    afh[mi], bfh[nj], acc[mi][nj], 0, 0, 0);
                acc[mi][nj] = __builtin_amdgcn_mfma_f32_16x16x32_bf16(
                    afh[mi], bfl[nj], acc[mi][nj], 0, 0, 0);
                acc[mi][nj] = __builtin_amdgcn_mfma_f32_16x16x32_bf16(
                    afl[mi], bfh[nj], acc[mi][nj], 0, 0, 0);
            }
    }

    int lrow = (lane >> 4) * 4, lcol = lane & 15;
#pragma unroll
    for (int mi = 0; mi < 4; mi++) {
        int row0 = bm + wm * 64 + mi * 16 + lrow;
#pragma unroll
        for (int nj = 0; nj < 4; nj++) {
            int col = bn + wn * 64 + nj * 16 + lcol;
            float bv = bias ? bias[col] : 0.f;
            f32x4 v = acc[mi][nj];
#pragma unroll
            for (int r = 0; r < 4; r++)
                Ct[(size_t)col * M + row0 + r] = v[r] + bv;
        }
    }
}

// ---------------- 2560-pt FFT (radix-5 + reg twiddle + 4x radix-4 + radix-2) --
// LDS index swizzle: kills Stockham stride-write bank conflicts. Bijective
// (upper bits unchanged), applied to EVERY bufA/bufB access.
__device__ __forceinline__ int swz(int a) { return a ^ ((a >> 4) & 15); }

// One radix-4 Stockham stage, S = 1<<LOGS in {1,4,16,64}.
template<int LOGS, int NT>
__device__ __forceinline__ void radix4_stage(const float2* __restrict__ X,
                                             float2* __restrict__ Y,
                                             const float2* __restrict__ w512x,
                                             int tid) {
    const int s = 1 << LOGS;
    for (int t = tid; t < 640; t += NT) {
        int sub = t >> 7, r = t & 127;
        int base = sub << 9;
        int q = r & (s - 1);
        int ps = r - q;                         // p'*s
        float2 x0 = X[swz(base + r)];
        float2 x1 = X[swz(base + r + 128)];
        float2 x2 = X[swz(base + r + 256)];
        float2 x3 = X[swz(base + r + 384)];
        float A0r = x0.x + x2.x, A0i = x0.y + x2.y;
        float B0r = x1.x + x3.x, B0i = x1.y + x3.y;
        float A1r = x0.x - x2.x, A1i = x0.y - x2.y;
        float B1r = x1.x - x3.x, B1i = x1.y - x3.y;
        float2 w1 = w512x[ps];                  // e^{-2pi i ps/512}
        float w2r = w1.x * w1.x - w1.y * w1.y;  // w1^2
        float w2i = 2.0f * w1.x * w1.y;
        float w3r = w2r * w1.x - w2i * w1.y;    // w1^3
        float w3i = w2r * w1.y + w2i * w1.x;
        float u1r = A1r + B1i, u1i = A1i - B1r; // A1 + (-i)B1
        float u2r = A0r - B0r, u2i = A0i - B0i;
        float u3r = A1r - B1i, u3i = A1i + B1r; // A1 + i B1
        int ob = base + q + 4 * ps;
        Y[swz(ob)]         = make_float2(A0r + B0r, A0i + B0i);
        Y[swz(ob + s)]     = make_float2(u1r * w1.x - u1i * w1.y,
                                         u1r * w1.y + u1i * w1.x);
        Y[swz(ob + 2 * s)] = make_float2(u2r * w2r - u2i * w2i,
                                         u2r * w2i + u2i * w2r);
        Y[swz(ob + 3 * s)] = make_float2(u3r * w3r - u3i * w3i,
                                         u3r * w3i + u3i * w3r);
    }
}

// Requires NT == 512 (thread tid owns n2 = tid in the radix-5 stage).
// INPUT IN REGISTERS: x[m] = signal[m*512 + tid].
// tw[k1-1] = e^{-2pi i * k1*tid / 2560}, precomputed once per block.
// Output: bufA[k1*512+k2] = DFT[k1 + 5*k2].
template<int NT>
__device__ void fft2560(const float2* x, float2* bufA, float2* bufB,
                        const float2* w512x, const float2* tw, int tid) {
    {
        const float w5r[5] = { 1.f,  0.30901699437494742f, -0.80901699437494742f,
                              -0.80901699437494742f,  0.30901699437494742f };
        const float w5i[5] = { 0.f, -0.95105651629515357f, -0.58778525229247312f,
                               0.58778525229247312f,  0.95105651629515357f };
#pragma unroll
        for (int k1 = 0; k1 < 5; k1++) {
            float ar = 0.f, ai = 0.f;
#pragma unroll
            for (int n1 = 0; n1 < 5; n1++) {
                int m = (n1 * k1) % 5;
                ar += x[n1].x * w5r[m] - x[n1].y * w5i[m];
                ai += x[n1].x * w5i[m] + x[n1].y * w5r[m];
            }
            if (k1 == 0) {
                bufB[swz(tid)] = make_float2(ar, ai);
            } else {
                float2 w = tw[k1 - 1];
                bufB[swz(k1 * 512 + tid)] =
                    make_float2(ar * w.x - ai * w.y, ar * w.y + ai * w.x);
            }
        }
    }
    __syncthreads();    // publish radix-5 writes; also fences prev-col bufA reads
    radix4_stage<0, NT>(bufB, bufA, w512x, tid); __syncthreads();
    radix4_stage<2, NT>(bufA, bufB, w512x, tid); __syncthreads();
    radix4_stage<4, NT>(bufB, bufA, w512x, tid); __syncthreads();
    radix4_stage<6, NT>(bufA, bufB, w512x, tid); __syncthreads();
    // final radix-2 (s=256, twiddle = 1)
    for (int t = tid; t < 1280; t += NT) {
        int sub = t >> 8, q = t & 255;
        int base = sub << 9;
        float2 a = bufB[swz(base + q)];
        float2 b = bufB[swz(base + q + 256)];
        bufA[swz(base + q)]       = make_float2(a.x + b.x, a.y + b.y);
        bufA[swz(base + q + 256)] = make_float2(a.x - b.x, a.y - b.y);
    }
    __syncthreads();    // publish bufA before epilogue reads; fences bufB reuse
}

// one workgroup (512 threads) per (DGRP-channel group, b)
__global__ __launch_bounds__(FFT_NT) void fft_fwd_kernel(
    const float* __restrict__ qt, const float* __restrict__ kt, float* __restrict__ Z)
{
    __shared__ float2 bufA[SEQ];
    __shared__ float2 bufB[SEQ];
    __shared__ float2 w512x[512];
    int d0 = blockIdx.x * DGRP;
    int b = blockIdx.y;
    int tid = threadIdx.x;
    {
        float sn, cs;
        sincosf(-6.283185307179586f * (float)tid / 512.0f, &sn, &cs);
        w512x[tid] = make_float2(cs, sn);
    }
    // radix-5 twiddles depend only on (k1, n2=tid): hoist to registers, once.
    float2 tw[4];
#pragma unroll
    for (int k1 = 1; k1 <= 4; k1++) {
        float sn, cs;
        sincosf(-2.4543692606170259e-3f * (float)(k1 * tid), &sn, &cs);
        tw[k1 - 1] = make_float2(cs, sn);
    }
    float accR[5], accI[5];
#pragma unroll
    for (int j = 0; j < 5; j++) { accR[j] = 0.f; accI[j] = 0.f; }

    for (int col = 0; col < DGRP; col++) {
        const float* qcol = qt + (size_t)(d0 + col) * MROWS + (size_t)b * SEQ;
        const float* kcol = kt + (size_t)(d0 + col) * MROWS + (size_t)b * SEQ;
        // direct register load (same elements the radix-5 stage consumes)
        float2 x[5];
#pragma unroll
        for (int m = 0; m < 5; m++)
            x[m] = make_float2(qcol[m * 512 + tid], kcol[m * 512 + tid]);
        fft2560<FFT_NT>(x, bufA, bufB, w512x, tw, tid);
#pragma unroll
        for (int j = 0; j < 5; j++) {
            int f = tid + FFT_NT * j;
            int fpos = (f % 5) * 512 + (f / 5);
            int g = f ? (SEQ - f) : 0;
            int gpos = (g % 5) * 512 + (g / 5);
            float2 Z1 = bufA[swz(fpos)], Z2 = bufA[swz(gpos)];
            accR[j] += 0.5f * (Z1.x * Z2.y + Z1.y * Z2.x);            // Im(Z1*Z2)/2
            accI[j] += 0.25f * ((Z1.x * Z1.x + Z1.y * Z1.y)
                              - (Z2.x * Z2.x + Z2.y * Z2.y));         // (|Z1|^2-|Z2|^2)/4
        }
    }
#pragma unroll
    for (int j = 0; j < 5; j++) {
        int f = tid + FFT_NT * j;
        int fpos = (f % 5) * 512 + (f / 5);
        atomicAdd(&Z[((size_t)b * SEQ + fpos) * 2 + 0], accR[j]);
        atomicAdd(&Z[((size_t)b * SEQ + fpos) * 2 + 1], accI[j]);
    }
}

__global__ __launch_bounds__(FFT_NT) void fft_inv_kernel(
    const float* __restrict__ Z, float* __restrict__ mc)
{
    __shared__ float2 bufA[SEQ];
    __shared__ float2 bufB[SEQ];
    __shared__ float2 w512x[512];
    int b = blockIdx.x;
    int tid = threadIdx.x;
    {
        float sn, cs;
        sincosf(-6.283185307179586f * (float)tid / 512.0f, &sn, &cs);
        w512x[tid] = make_float2(cs, sn);
    }
    float2 tw[4];
#pragma unroll
    for (int k1 = 1; k1 <= 4; k1++) {
        float sn, cs;
        sincosf(-2.4543692606170259e-3f * (float)(k1 * tid), &sn, &cs);
        tw[k1 - 1] = make_float2(cs, sn);
    }
    // direct register load with the same index map the loader used
    float2 x[5];
#pragma unroll
    for (int m = 0; m < 5; m++) {
        int i = m * 512 + tid;
        int k1 = i % 5, k2 = i / 5;
        float zr = Z[((size_t)b * SEQ + k1 * 512 + k2) * 2 + 0];
        float zi = Z[((size_t)b * SEQ + k1 * 512 + k2) * 2 + 1];
        x[m] = make_float2(zr, -zi);
    }
    fft2560<FFT_NT>(x, bufA, bufB, w512x, tw, tid);
    const float scale = 1.0f / (2560.0f * 512.0f);
    for (int j = tid; j < SEQ; j += FFT_NT) {
        int k1 = j >> 9, k2 = j & 511;
        mc[(size_t)b * SEQ + k1 + 5 * k2] = bufA[swz(j)].x * scale;
    }
}

// ---------------- top-7 + softmax per batch ----------------
__global__ __launch_bounds__(256) void topk_kernel(
    const float* __restrict__ mc, float* __restrict__ wts, int* __restrict__ dels)
{
    __shared__ float cv[SEQ];
    __shared__ float rv[256];
    __shared__ int   ri[256];
    __shared__ float topv[TOPK];
    __shared__ int   topi[TOPK];
    int b = blockIdx.x, tid = threadIdx.x;
    for (int i = tid; i < SEQ; i += 256) cv[i] = mc[(size_t)b * SEQ + i];
    __syncthreads();
    for (int it = 0; it < TOPK; it++) {
        float bv = -2e30f; int bi = 1 << 30;
        for (int i = tid; i < SEQ; i += 256) {
            float v = cv[i];
            if (v > bv || (v == bv && i < bi)) { bv = v; bi = i; }
        }
        rv[tid] = bv; ri[tid] = bi;
        __syncthreads();
        for (int off = 128; off > 0; off >>= 1) {
            if (tid < off) {
                float v2 = rv[tid + off]; int i2 = ri[tid + off];
                if (v2 > rv[tid] || (v2 == rv[tid] && i2 < ri[tid])) {
                    rv[tid] = v2; ri[tid] = i2;
                }
            }
            __syncthreads();
        }
        if (tid == 0) { topv[it] = rv[0]; topi[it] = ri[0]; cv[ri[0]] = -1e30f; }
        __syncthreads();
    }
    if (tid == 0) {
        float mx = topv[0];
        float e[TOPK], ssum = 0.f;
        for (int i = 0; i < TOPK; i++) { e[i] = expf(topv[i] - mx); ssum += e[i]; }
        for (int i = 0; i < TOPK; i++) {
            wts[b * TOPK + i] = e[i] / ssum;
            dels[b * TOPK + i] = topi[i];
        }
    }
}

// ------- fused delay aggregation + bias + residual (float4 vectorized) -------
__global__ void agg_res_kernel(const float* __restrict__ u, const float* __restrict__ x,
                               const float* __restrict__ cb,
                               const float* __restrict__ wts, const int* __restrict__ dels,
                               float* __restrict__ x1) {
    size_t i4 = ((size_t)blockIdx.x * 256 + threadIdx.x) * 4;
    if (i4 >= SD) return;
    int d = (int)(i4 & (DMODEL - 1));
    size_t r = i4 >> 9;
    int s = (int)(r % SEQ);
    int b = (int)(r / SEQ);
    float4 xx = *(const float4*)(x + i4);
    float4 cc = *(const float4*)(cb + d);
    float a0 = cc.x + xx.x, a1 = cc.y + xx.y, a2 = cc.z + xx.z, a3 = cc.w + xx.w;
    const float* ub = u + (size_t)b * SEQ * DMODEL + d;
#pragma unroll
    for (int i = 0; i < TOPK; i++) {
        int del = dels[b * TOPK + i];
        float w = wts[b * TOPK + i];
        int ss = s + del; if (ss >= SEQ) ss -= SEQ;
        float4 uu = *(const float4*)(ub + (size_t)ss * DMODEL);
        a0 += w * uu.x; a1 += w * uu.y; a2 += w * uu.z; a3 += w * uu.w;
    }
    *(float4*)(x1 + i4) = make_float4(a0, a1, a2, a3);
}

// --------- x - moving_avg(x): running-window (r5/r7 proven scalar form) ------
// TLP-fed: 640 blocks x 256 threads; serial window update per thread.
#define MA_MODE_PLAIN 0
#define MA_MODE_BF    1
#define MA_MODE_SPLIT 2
template<int MODE>
__device__ __forceinline__ void ma_run_body(
    const float* __restrict__ x, float* __restrict__ out,
    unsigned short* __restrict__ o1, unsigned short* __restrict__ o2)
{
    int tid = threadIdx.x;
    int s0 = blockIdx.x * 128;
    int d  = blockIdx.y * 256 + tid;
    int b  = blockIdx.z;
    const float* xb = x + (size_t)b * SEQ * DMODEL + d;
    float sum = 0.f;
#pragma unroll
    for (int j = -12; j <= 12; j++) {
        int ss = s0 + j;
        ss = ss < 0 ? 0 : (ss > SEQ - 1 ? SEQ - 1 : ss);
        sum += xb[(size_t)ss * DMODEL];
    }
    for (int s = s0; s < s0 + 128; s++) {
        float v = xb[(size_t)s * DMODEL] - sum * (1.0f / 25.0f);
        size_t o = ((size_t)b * SEQ + s) * DMODEL + d;
        out[o] = v;
        if (MODE == MA_MODE_BF) {
            o1[o] = f2bf(v);
        } else if (MODE == MA_MODE_SPLIT) {
            unsigned short h = f2bf(v);
            o1[o] = h;
            o2[o] = f2bf(v - bf2f(h));
        }
        int add = s + 13; if (add > SEQ - 1) add = SEQ - 1;
        int sub = s - 12; if (sub < 0) sub = 0;
        sum += xb[(size_t)add * DMODEL] - xb[(size_t)sub * DMODEL];
    }
}
__global__ __launch_bounds__(256) void ma_sub_kernel(
    const float* __restrict__ x, float* __restrict__ out) {
    ma_run_body<MA_MODE_PLAIN>(x, out, nullptr, nullptr);
}
__global__ __launch_bounds__(256) void ma_sub_bf_kernel(
    const float* __restrict__ x, float* __restrict__ out,
    unsigned short* __restrict__ obf) {
    ma_run_body<MA_MODE_BF>(x, out, obf, nullptr);
}
__global__ __launch_bounds__(256) void ma_sub_split_kernel(
    const float* __restrict__ x, float* __restrict__ out,
    unsigned short* __restrict__ hi, unsigned short* __restrict__ lo) {
    ma_run_body<MA_MODE_SPLIT>(x, out, hi, lo);
}

// ---------------- layernorm over last dim ----------------
__global__ __launch_bounds__(256) void ln_kernel(
    const float* __restrict__ x, const float* __restrict__ g,
    const float* __restrict__ be, float* __restrict__ xh)
{
    int row = blockIdx.x;
    int tid = threadIdx.x;
    __shared__ float red[256];
    const float* xr = x + (size_t)row * DMODEL;
    float v0 = xr[tid], v1 = xr[tid + 256];
    red[tid] = v0 + v1;
    __syncthreads();
    for (int off = 128; off > 0; off >>= 1) {
        if (tid < off) red[tid] += red[tid + off];
        __syncthreads();
    }
    float mu = red[0] / (float)DMODEL;
    __syncthreads();
    float d0 = v0 - mu, d1 = v1 - mu;
    red[tid] = d0 * d0 + d1 * d1;
    __syncthreads();
    for (int off = 128; off > 0; off >>= 1) {
        if (tid < off) red[tid] += red[tid + off];
        __syncthreads();
    }
    float inv = rsqrtf(red[0] / (float)DMODEL + 1e-5f);
    xh[(size_t)row * DMODEL + tid]       = d0 * inv * g[tid] + be[tid];
    xh[(size_t)row * DMODEL + tid + 256] = d1 * inv * g[tid + 256] + be[tid + 256];
}

// ------ per-(b,d) mean over sequence (float4 cols, atomic partials) ----------
__global__ __launch_bounds__(256) void colmean_kernel(
    const float* __restrict__ xh, float* __restrict__ cm) {
    int q = blockIdx.x * 256 + threadIdx.x;     // 0..2047, 4 cols each
    int idx = q * 4;                            // (b,d) base
    int d = idx & (DMODEL - 1), b = idx >> 9;
    int s0 = blockIdx.y * 128;
    const float* xb = xh + (size_t)b * SEQ * DMODEL + d;
    float a0 = 0.f, a1 = 0.f, a2 = 0.f, a3 = 0.f;
    for (int s = s0; s < s0 + 128; s++) {
        float4 v = *(const float4*)(xb + (size_t)s * DMODEL);
        a0 += v.x; a1 += v.y; a2 += v.z; a3 += v.w;
    }
    atomicAdd(&cm[idx + 0], a0 * (1.0f / (float)SEQ));
    atomicAdd(&cm[idx + 1], a1 * (1.0f / (float)SEQ));
    atomicAdd(&cm[idx + 2], a2 * (1.0f / (float)SEQ));
    atomicAdd(&cm[idx + 3], a3 * (1.0f / (float)SEQ));
}

__global__ __launch_bounds__(256) void final_kernel(
    const float* __restrict__ xh, const float* __restrict__ cm,
    const float* __restrict__ Wp, const float* __restrict__ bp,
    float* __restrict__ out)
{
    int b = blockIdx.y, chunk = blockIdx.x;
    int tid = threadIdx.x;
    const size_t per = (size_t)SEQ * DMODEL / 64;   // 20480, %1024 == 0
    size_t start = (size_t)chunk * per;
    float acc = 0.f;
    for (size_t i = start + tid * 4; i < start + per; i += 1024) {
        int d = (int)(i & (DMODEL - 1));
        float4 v = *(const float4*)(xh + (size_t)b * SEQ * DMODEL + i);
        float4 c = *(const float4*)(cm + b * DMODEL + d);
        float4 w = *(const float4*)(Wp + i);
        acc += gelu_f(v.x - c.x) * w.x + gelu_f(v.y - c.y) * w.y
             + gelu_f(v.z - c.z) * w.z + gelu_f(v.w - c.w) * w.w;
    }
    __shared__ float red[256];
    red[tid] = acc;
    __syncthreads();
    for (int off = 128; off > 0; off >>= 1) {
        if (tid < off) red[tid] += red[tid + off];
        __syncthreads();
    }
    if (tid == 0) {
        atomicAdd(&out[b], red[0]);
        if (chunk == 0) atomicAdd(&out[b], bp[0]);
    }
}

// ---------------- orchestration: 3-buffer rotation, NO input/output aliasing ----
extern "C" void kernel_launch(void* const* d_in, const int* in_sizes, int n_in,
                              void* d_out, int out_size, void* d_ws, size_t ws_size,
                              hipStream_t stream) {
    const float* data  = (const float*)d_in[0];
    const float* mask  = (const float*)d_in[1];
    const float* Wemb  = (const float*)d_in[2];
    const float* Wq    = (const float*)d_in[3];
    const float* bq    = (const float*)d_in[4];
    const float* Wk    = (const float*)d_in[5];
    const float* bk    = (const float*)d_in[6];
    const float* Wv    = (const float*)d_in[7];
    const float* bv    = (const float*)d_in[8];
    const float* Wo    = (const float*)d_in[9];
    const float* bo    = (const float*)d_in[10];
    const float* Wc1   = (const float*)d_in[11];
    const float* Wc2   = (const float*)d_in[12];
    const float* gamma = (const float*)d_in[13];
    const float* beta  = (const float*)d_in[14];
    const float* Wp    = (const float*)d_in[15];
    const float* bp    = (const float*)d_in[16];
    float* out = (float*)d_out;

    float* buf0 = (float*)d_ws;
    float* buf1 = buf0 + SD;
    float* buf2 = buf1 + SD;

    unsigned short* WstkH = (unsigned short*)(buf2 + SD);   // 2*512*512 stacked q/k hi
    unsigned short* WstkL = WstkH + 2 * DMODEL * DMODEL;    // stacked q/k lo
    unsigned short* Wvot  = WstkL + 2 * DMODEL * DMODEL;    // bf16 [N][K] of Wv@Wo
    unsigned short* Wc1t  = Wvot + DMODEL * DMODEL;         // [2048][512]
    unsigned short* Wc2t  = Wc1t + (size_t)DMODEL * DFF;    // [512][2048]
    float* WvoF = (float*)(Wc2t + (size_t)DMODEL * DFF);    // fp32 Wv@Wo (512x512)
    float* CB   = WvoF + (size_t)DMODEL * DMODEL;           // cb = bv@Wo + bo
    float* Bstk = CB + DMODEL;                              // stacked q/k bias (1024)
    float* Zb = Bstk + 1024;
    float* MC = Zb + (size_t)BATCH * SEQ * 2;
    float* WT = MC + (size_t)BATCH * SEQ;
    int*   DL = (int*)(WT + BATCH * TOPK);
    float* CM = (float*)(DL + BATCH * TOPK);

    const int NB  = (int)((SD + 255) / 256);
    const int NB4 = (int)((SD / 4 + 255) / 256);
    dim3 gMA(SEQ / 128, 2, BATCH);              // (20, 2, 16) running-window MA

    float* X  = buf0;   // x fp32
    float* HL = buf1;   // hi/lo pool
    float* S  = buf2;   // scratch

    // embed + fused hi/lo split (vectorized): hi -> upper half of HL, lo -> lower
    embed_kernel<<<MROWS / 2, 256, 0, stream>>>(data, mask, Wemb, X,
                                                (unsigned short*)HL + SD,
                                                (unsigned short*)HL);

    // 1-D swizzled GEMM grids: blocks = gridM*gridN (gridM % 8 == 0)
    const int gSqBlocks = (MROWS / 128) * (DMODEL / 128);       // 320*4 = 1280
    const int gF1Blocks = (FFN_CHUNK / 128) * (DFF / 128);      // 160*16 = 2560
    const int gF2Blocks = (FFN_CHUNK / 128) * (DMODEL / 128);   // 160*4 = 640

    for (int l = 0; l < NLAYERS; l++) {
        const float* wq = Wq + (size_t)l * DMODEL * DMODEL;
        const float* wk = Wk + (size_t)l * DMODEL * DMODEL;
        const float* wv = Wv + (size_t)l * DMODEL * DMODEL;
        const float* wo = Wo + (size_t)l * DMODEL * DMODEL;
        const float* bqL = bq + (size_t)l * DMODEL;
        const float* bkL = bk + (size_t)l * DMODEL;
        const float* bvL = bv + (size_t)l * DMODEL;
        const float* boL = bo + (size_t)l * DMODEL;
        const float* wc1 = Wc1 + (size_t)l * DMODEL * DFF;
        const float* wc2 = Wc2 + (size_t)l * DFF * DMODEL;

        unsigned short* Lbf = (unsigned short*)HL;      // x_lo (lower half)
        unsigned short* Hbf = Lbf + SD;                 // x_hi (upper half)
        float* qtf = S;                                 // q cols (MROWS*256)
        float* ktf = S + (size_t)MROWS * CHUNK_D;       // k cols

        dim3 gT(DMODEL / 32, DMODEL / 32);
        transpose_split_stk_kernel<<<gT, 256, 0, stream>>>(wq, WstkH, WstkL, 0);
        transpose_split_stk_kernel<<<gT, 256, 0, stream>>>(wk, WstkH, WstkL, 1);
        stack_bias_kernel<<<4, 256, 0, stream>>>(bqL, bkL, Bstk);
        wvo_kernel<<<DMODEL, 256, 0, stream>>>(wv, wo, WvoF);
        transpose_bf16_kernel<<<gT, 256, 0, stream>>>(WvoF, Wvot, DMODEL, DMODEL);
        cbias_kernel<<<2, 256, 0, stream>>>(bvL, wo, boL, CB);
        transpose_bf16_kernel<<<dim3(DFF / 32, DMODEL / 32), 256, 0, stream>>>(wc1, Wc1t, DMODEL, DFF);
        transpose_bf16_kernel<<<dim3(DMODEL / 32, DFF / 32), 256, 0, stream>>>(wc2, Wc2t, DFF, DMODEL);

        // q&k stacked: one split GEMM per 256-col chunk into S (N=512 covers both)
        hipMemsetAsync(Zb, 0, (size_t)BATCH * SEQ * 2 * sizeof(float), stream);
        for (int c = 0; c < DMODEL / CHUNK_D; c++) {
            gemm_qk_split_kernel<<<gSqBlocks, 256, 0, stream>>>(
                Hbf, Lbf, WstkH + (size_t)c * 512 * DMODEL,
                WstkL + (size_t)c * 512 * DMODEL, Bstk + c * 512,
                S, MROWS, DMODEL, DMODEL / 128);
            fft_fwd_kernel<<<dim3(CHUNK_D / DGRP, BATCH), FFT_NT, 0, stream>>>(qtf, ktf, Zb);
        }
        fft_inv_kernel<<<BATCH, FFT_NT, 0, stream>>>(Zb, MC);
        topk_kernel<<<BATCH, 256, 0, stream>>>(MC, WT, DL);

        // u = x@(Wv@Wo) -> S fp32 (qtf/ktf dead)
        gemm_mfma_kernel<<<gSqBlocks, 256, 0, stream>>>(Hbf, Wvot, nullptr, nullptr, S,
                                                        MROWS, DMODEL, DMODEL, 0, 0,
                                                        DMODEL / 128);
        // x1 = sum w_i roll(u) + cb + x -> HL as fp32 (x hi/lo dead)
        agg_res_kernel<<<NB4, 256, 0, stream>>>(S, X, CB, WT, DL, HL);
        // x2 = x1 - MA(x1): fp32 -> X (x dead), bf16 -> S (u dead). No aliasing.
        ma_sub_bf_kernel<<<gMA, 256, 0, stream>>>(HL, X, (unsigned short*)S);
        // FFN in 2 row-chunks: gelu bf16 fills HL exactly (x1 dead);
        // z in-place over X (res==out, same-index).
        for (int c = 0; c < MROWS / FFN_CHUNK; c++) {
            const unsigned short* x2c = (unsigned short*)S + (size_t)c * FFN_CHUNK * DMODEL;
            float* xz = X + (size_t)c * FFN_CHUNK * DMODEL;
            gemm_mfma_kernel<<<gF1Blocks, 256, 0, stream>>>(x2c, Wc1t, nullptr, nullptr,
                                                            (unsigned short*)HL,
                                                            FFN_CHUNK, DFF, DMODEL, 1, 1,
                                                            DFF / 128);
            gemm_mfma_kernel<<<gF2Blocks, 256, 0, stream>>>((unsigned short*)HL, Wc2t,
                                                            nullptr, xz, xz,
                                                            FFN_CHUNK, DMODEL, DFF, 0, 0,
                                                            DMODEL / 128);
        }
        // h = z - MA(z): z in X -> h fp32 -> S (+ hi/lo -> HL if another layer)
        if (l + 1 < NLAYERS)
            ma_sub_split_kernel<<<gMA, 256, 0, stream>>>(
                X, S, (unsigned short*)HL + SD, (unsigned short*)HL);
        else
            ma_sub_kernel<<<gMA, 256, 0, stream>>>(X, S);
        // rotate: next layer's x is in S
        float* tmp = X; X = S; S = tmp;
    }

    // final h is in X; use HL for xh
    ln_kernel<<<MROWS, 256, 0, stream>>>(X, gamma, beta, HL);
    hipMemsetAsync(CM, 0, (size_t)BATCH * DMODEL * sizeof(float), stream);
    colmean_kernel<<<dim3(8, 20), 256, 0, stream>>>(HL, CM);
    hipMemsetAsync(out, 0, (size_t)out_size * sizeof(float), stream);
    final_kernel<<<dim3(64, BATCH), 256, 0, stream>>>(HL, CM, Wp, bp, out);
}

// Round 14
// 2002.811 us; speedup vs baseline: 1.0528x; 1.0528x over previous
//
#include <hip/hip_runtime.h>
#include <math.h>

// ---------------- problem constants ----------------
#define BATCH 16
#define L_CYC 20
#define CDL 128
#define SEQ 2560            // L_CYC * CDL
#define ENC_IN 3
#define DMODEL 512
#define DFF 2048
#define NLAYERS 2
#define TOPK 7
#define MROWS (BATCH*SEQ)   // 40960
#define SD ((size_t)BATCH * SEQ * DMODEL)   // 20,971,520
#define FFN_CHUNK 20480     // 2 chunks; 20480*2048 ushorts == SD*4 bytes exactly
#define CHUNK_D 256         // q/k column-chunk width
#define DGRP 8              // FFT channels per workgroup (proven; 4 regressed r6)
#define FFT_NT 512          // threads per FFT block (round-15 proven)

typedef short bf16x8 __attribute__((ext_vector_type(8)));
typedef float f32x4 __attribute__((ext_vector_type(4)));

// fast gelu: A&S 7.1.26 erf (|err| <= 1.5e-7), hw exp; ~14 VALU ops vs ~30 libm
__device__ __forceinline__ float gelu_f(float x) {
    float z = x * 0.70710678118654752f;
    float az = fabsf(z);
    float t = __builtin_amdgcn_rcpf(1.0f + 0.3275911f * az);
    float poly = t * (0.254829592f + t * (-0.284496736f + t * (1.421413741f
               + t * (-1.453152027f + t * 1.061405429f))));
    float e = __expf(-az * az);
    float erfv = 1.0f - poly * e;
    erfv = copysignf(erfv, z);
    return 0.5f * x * (1.0f + erfv);
}
__device__ __forceinline__ unsigned short f2bf(float f) {
    unsigned int u = __float_as_uint(f);
    u += 0x7fff + ((u >> 16) & 1);          // RNE
    return (unsigned short)(u >> 16);
}
__device__ __forceinline__ float bf2f(unsigned short h) {
    return __uint_as_float(((unsigned int)h) << 16);
}
// XCD-aware swizzle: 1-D block id p -> (row-group g, n-tile n) with all G
// n-tiles of g on the same XCD (round-robin p%8). Requires gridM % 8 == 0.
__device__ __forceinline__ void xcd_map(int p, int G, int& g, int& n) {
    int a = p >> 3;
    n = a % G;
    g = (a / G) * 8 + (p & 7);
}
// async global->LDS, 16B per lane; LDS dest is wave-uniform base + lane*16.
__device__ __forceinline__ void gload16(const unsigned short* g, unsigned short* l) {
    typedef unsigned int u32;
    __builtin_amdgcn_global_load_lds(
        (const __attribute__((address_space(1))) u32*)g,
        (__attribute__((address_space(3))) u32*)l, 16, 0, 0);
}

// -------- embed: mask + reshape + circular conv1d(k=3) + fused hi/lo split ----
// float4/ushort4 stores (r4 agg_res pattern): 2 rows/block, 4 cols/thread.
__global__ __launch_bounds__(256) void embed_kernel(
    const float* __restrict__ data, const float* __restrict__ mask,
    const float* __restrict__ Wemb, float* __restrict__ h,
    unsigned short* __restrict__ hi, unsigned short* __restrict__ lo) {
    __shared__ float xv[2][9];      // [local row][c*3 + t]
    int tid = threadIdx.x;
    size_t r0 = (size_t)blockIdx.x * 2;
    if (tid < 18) {
        int lr = tid / 9, k = tid % 9;
        int t = k / 3, c = k % 3;
        size_t r = r0 + lr;
        int s = (int)(r % SEQ);
        int b = (int)(r / SEQ);
        int u = s - 1 + t;
        if (u < 0) u += SEQ;
        if (u >= SEQ) u -= SEQ;
        int cyc = u >> 7, pos = u & 127;
        float mk = mask[b * L_CYC + cyc];
        xv[lr][c * 3 + t] = (mk == 0.f) ? 0.f
            : data[(((size_t)b * L_CYC + cyc) * ENC_IN + c) * CDL + pos];
    }
    __syncthreads();
    int lr = tid >> 7;
    int dm = (tid & 127) * 4;
    size_t idx = (r0 + lr) * DMODEL + dm;
    float a[4];
#pragma unroll
    for (int q = 0; q < 4; q++) {
        float acc = 0.f;
#pragma unroll
        for (int j = 0; j < 9; j++) acc += xv[lr][j] * Wemb[(dm + q) * 9 + j];
        a[q] = acc;
    }
    *(float4*)(h + idx) = make_float4(a[0], a[1], a[2], a[3]);
    ushort4 hv = make_ushort4(f2bf(a[0]), f2bf(a[1]), f2bf(a[2]), f2bf(a[3]));
    *(ushort4*)(hi + idx) = hv;
    ushort4 lv = make_ushort4(f2bf(a[0] - bf2f(hv.x)), f2bf(a[1] - bf2f(hv.y)),
                              f2bf(a[2] - bf2f(hv.z)), f2bf(a[3] - bf2f(hv.w)));
    *(ushort4*)(lo + idx) = lv;
}

// ---------------- transpose W[K][N] fp32 -> Wt[N][K] bf16 ----------------
__global__ __launch_bounds__(256) void transpose_bf16_kernel(
    const float* __restrict__ W, unsigned short* __restrict__ Wt, int K, int N) {
    __shared__ float t[32][33];
    int n0 = blockIdx.x * 32, k0 = blockIdx.y * 32;
    int c = threadIdx.x & 31, r = threadIdx.x >> 5;   // r: 0..7
    for (int i = 0; i < 4; i++)
        t[r + i * 8][c] = W[(size_t)(k0 + r + i * 8) * N + n0 + c];
    __syncthreads();
    for (int i = 0; i < 4; i++)
        Wt[(size_t)(n0 + r + i * 8) * K + k0 + c] = f2bf(t[c][r + i * 8]);
}

// ---- transpose 512x512 W -> STACKED hi/lo bf16: q/k interleaved per 256-chunk ----
__global__ __launch_bounds__(256) void transpose_split_stk_kernel(
    const float* __restrict__ W, unsigned short* __restrict__ WtH,
    unsigned short* __restrict__ WtL, int which) {
    __shared__ float t[32][33];
    int n0 = blockIdx.x * 32, k0 = blockIdx.y * 32;
    int c = threadIdx.x & 31, r = threadIdx.x >> 5;
    for (int i = 0; i < 4; i++)
        t[r + i * 8][c] = W[(size_t)(k0 + r + i * 8) * DMODEL + n0 + c];
    __syncthreads();
    for (int i = 0; i < 4; i++) {
        int n = n0 + r + i * 8;
        int row = (n & 255) + ((n >> 8) * 512) + which * 256;
        float v = t[c][r + i * 8];
        unsigned short h = f2bf(v);
        size_t o = (size_t)row * DMODEL + k0 + c;
        WtH[o] = h;
        WtL[o] = f2bf(v - bf2f(h));
    }
}

// ---------------- stacked bias ----------------
__global__ void stack_bias_kernel(const float* __restrict__ bq,
                                  const float* __restrict__ bk, float* __restrict__ bstk) {
    int i = blockIdx.x * 256 + threadIdx.x;     // 0..1023
    if (i >= 1024) return;
    int c = i >> 9, j = i & 511;
    bstk[i] = (j < 256) ? bq[c * 256 + j] : bk[c * 256 + (j - 256)];
}

// ---------------- Wvo = Wv @ Wo (fp32, per layer; 512 blocks) ----------------
__global__ __launch_bounds__(256) void wvo_kernel(
    const float* __restrict__ Wv, const float* __restrict__ Wo,
    float* __restrict__ Wvo) {
    __shared__ float row[DMODEL];
    int k = blockIdx.x;
    int tid = threadIdx.x;
    for (int j = tid; j < DMODEL; j += 256) row[j] = Wv[(size_t)k * DMODEL + j];
    __syncthreads();
    float a0 = 0.f, a1 = 0.f;
    for (int j = 0; j < DMODEL; j++) {
        float wv = row[j];
        a0 += wv * Wo[(size_t)j * DMODEL + tid];
        a1 += wv * Wo[(size_t)j * DMODEL + tid + 256];
    }
    Wvo[(size_t)k * DMODEL + tid] = a0;
    Wvo[(size_t)k * DMODEL + tid + 256] = a1;
}

// ---------------- cb = bv @ Wo + bo ----------------
__global__ void cbias_kernel(const float* __restrict__ bv, const float* __restrict__ Wo,
                             const float* __restrict__ bo, float* __restrict__ cb) {
    int n = blockIdx.x * 256 + threadIdx.x;
    if (n >= DMODEL) return;
    float acc = bo[n];
    for (int j = 0; j < DMODEL; j++) acc += bv[j] * Wo[(size_t)j * DMODEL + n];
    cb[n] = acc;
}

// ------ bf16 MFMA GEMM: BK=64, single-buffer 2-barrier, both-sides XOR swizzle
// (proven optimum; BK axis fully mapped: 32=99us, 64=85us, 128=106us r13.
// Occupancy-costing variants regressed: r3 dbuf, r6 dbuf64KB, r8 256-tile.)
#define BK 64
__global__ __launch_bounds__(256) void gemm_mfma_kernel(
    const unsigned short* __restrict__ A, const unsigned short* __restrict__ Wt,
    const float* __restrict__ bias, const float* res,
    void* Cout, int M, int N, int K, int act, int outMode, int gridN)
{
    __shared__ unsigned short As[128 * 64];   // 16KB
    __shared__ unsigned short Bs[128 * 64];   // 16KB
    int tid = threadIdx.x;
    int wave = tid >> 6, lane = tid & 63;
    int wm = wave & 1, wn = wave >> 1;
    int gblk, nblk;
    xcd_map(blockIdx.x, gridN, gblk, nblk);
    int bm = gblk * 128, bn = nblk * 128;

    int r8 = lane >> 3;                       // row within 8-row group (== row&7)
    int swc = ((lane & 7) ^ r8) * 8;          // pre-swizzled global col (shorts)
    const unsigned short* Agb = A  + (size_t)(bm + wave * 32 + r8) * K + swc;
    const unsigned short* Bgb = Wt + (size_t)(bn + wave * 32 + r8) * K + swc;
    unsigned short* AsW = As + wave * 32 * 64;
    unsigned short* BsW = Bs + wave * 32 * 64;

    f32x4 acc[4][4] = {};
    int frow = lane & 15;
    int fj = lane >> 4;                       // 16B slot within 64B k-half
    int s7 = frow & 7;

    for (int k0 = 0; k0 < K; k0 += BK) {
        __syncthreads();                      // previous tile's reads complete
#pragma unroll
        for (int i = 0; i < 4; i++) {
            gload16(Agb + (size_t)(i * 8) * K + k0, AsW + i * 8 * 64);
            gload16(Bgb + (size_t)(i * 8) * K + k0, BsW + i * 8 * 64);
        }
        asm volatile("s_waitcnt vmcnt(0)" ::: "memory");
        __syncthreads();
#pragma unroll
        for (int kk = 0; kk < 2; kk++) {
            int c16 = (((kk << 2) | fj) ^ s7) << 3;   // swizzled short offset
            bf16x8 af[4], bfv[4];
#pragma unroll
            for (int mi = 0; mi < 4; mi++)
                af[mi] = *(const bf16x8*)&As[(wm * 64 + mi * 16 + frow) * 64 + c16];
#pragma unroll
            for (int nj = 0; nj < 4; nj++)
                bfv[nj] = *(const bf16x8*)&Bs[(wn * 64 + nj * 16 + frow) * 64 + c16];
#pragma unroll
            for (int mi = 0; mi < 4; mi++)
#pragma unroll
                for (int nj = 0; nj < 4; nj++)
                    acc[mi][nj] = __builtin_amdgcn_mfma_f32_16x16x32_bf16(
                        af[mi], bfv[nj], acc[mi][nj], 0, 0, 0);
        }
    }

    int lrow = (lane >> 4) * 4, lcol = lane & 15;
#pragma unroll
    for (int mi = 0; mi < 4; mi++) {
        int row0 = bm + wm * 64 + mi * 16 + lrow;
#pragma unroll
        for (int nj = 0; nj < 4; nj++) {
            int col = bn + wn * 64 + nj * 16 + lcol;
            float bv = bias ? bias[col] : 0.f;
            f32x4 v = acc[mi][nj];
#pragma unroll
            for (int r = 0; r < 4; r++) {
                int row = row0 + r;
                float x = v[r] + bv;
                if (res) x += res[(size_t)row * N + col];
                if (act == 1) x = gelu_f(x);
                if (outMode == 0) ((float*)Cout)[(size_t)row * N + col] = x;
                else              ((unsigned short*)Cout)[(size_t)row * N + col] = f2bf(x);
            }
        }
    }
}

// -- split-precision MFMA GEMM for q/k (BK=32 + T2 slot swizzle both sides) ---
// Output fp32 TRANSPOSED: Ct[col*M + row]. N=512 stacked covers q&k. gridN=4.
#define QBK 32
__global__ __launch_bounds__(256) void gemm_qk_split_kernel(
    const unsigned short* __restrict__ Ahi, const unsigned short* __restrict__ Alo,
    const unsigned short* __restrict__ Whi, const unsigned short* __restrict__ Wlo,
    const float* __restrict__ bias, float* __restrict__ Ct, int M, int K, int gridN)
{
    __shared__ unsigned short AsH[128 * 32];
    __shared__ unsigned short AsL[128 * 32];
    __shared__ unsigned short BsH[128 * 32];
    __shared__ unsigned short BsL[128 * 32];
    int tid = threadIdx.x;
    int wave = tid >> 6, lane = tid & 63;
    int wm = wave & 1, wn = wave >> 1;
    int gblk, nblk;
    xcd_map(blockIdx.x, gridN, gblk, nblk);
    int bm = gblk * 128, bn = nblk * 128;

    int lrs = lane >> 2;                                    // row within 16-row chunk
    int lk  = (((lane & 3) ^ ((lane >> 3) & 3))) * 8;       // pre-swizzled source col

    f32x4 acc[4][4] = {};
    int frow = lane & 15;
    int fk = (((lane >> 4) ^ ((frow >> 1) & 3))) * 8;       // swizzled read slot

    for (int k0 = 0; k0 < K; k0 += QBK) {
        __syncthreads();
#pragma unroll
        for (int i = 0; i < 2; i++) {
            int j = wave * 2 + i;
            int row = j * 16 + lrs;
            size_t oa = (size_t)(bm + row) * K + k0 + lk;
            size_t ob = (size_t)(bn + row) * K + k0 + lk;
            gload16(Ahi + oa, AsH + j * 512);
            gload16(Alo + oa, AsL + j * 512);
            gload16(Whi + ob, BsH + j * 512);
            gload16(Wlo + ob, BsL + j * 512);
        }
        asm volatile("s_waitcnt vmcnt(0)" ::: "memory");
        __syncthreads();
        bf16x8 afh[4], afl[4], bfh[4], bfl[4];
#pragma unroll
        for (int mi = 0; mi < 4; mi++) {
            int o = (wm * 64 + mi * 16 + frow) * 32 + fk;
            afh[mi] = *(const bf16x8*)&AsH[o];
            afl[mi] = *(const bf16x8*)&AsL[o];
        }
#pragma unroll
        for (int nj = 0; nj < 4; nj++) {
            int o = (wn * 64 + nj * 16 + frow) * 32 + fk;
            bfh[nj] = *(const bf16x8*)&BsH[o];
            bfl[nj] = *(const bf16x8*)&BsL[o];
        }
#pragma unroll
        for (int mi = 0; mi < 4; mi++)
#pragma unroll
            for (int nj = 0; nj < 4; nj++) {
                acc[mi][nj] = __builtin_amdgcn_mfma_f32_16x16x32_bf16(
                    afh[mi], bfh[nj], acc[mi][nj], 0, 0, 0);
                acc[mi][nj] = __builtin_amdgcn_mfma_f32_16x16x32_bf16(
                    afh[mi], bfl[nj], acc[mi][nj], 0, 0, 0);
                acc[mi][nj] = __builtin_amdgcn_mfma_f32_16x16x32_bf16(
                    afl[mi], bfh[nj], acc[mi][nj], 0, 0, 0);
            }
    }

    int lrow = (lane >> 4) * 4, lcol = lane & 15;
#pragma unroll
    for (int mi = 0; mi < 4; mi++) {
        int row0 = bm + wm * 64 + mi * 16 + lrow;
#pragma unroll
        for (int nj = 0; nj < 4; nj++) {
            int col = bn + wn * 64 + nj * 16 + lcol;
            float bv = bias ? bias[col] : 0.f;
            f32x4 v = acc[mi][nj];
#pragma unroll
            for (int r = 0; r < 4; r++)
                Ct[(size_t)col * M + row0 + r] = v[r] + bv;
        }
    }
}

// ---------------- 2560-pt FFT (radix-5 + reg twiddle + 4x radix-4 + radix-2) --
// LDS index swizzle: kills Stockham stride-write bank conflicts. Bijective
// (upper bits unchanged), applied to EVERY bufA/bufB access.
__device__ __forceinline__ int swz(int a) { return a ^ ((a >> 4) & 15); }

// One radix-4 Stockham stage, S = 1<<LOGS in {1,4,16,64}.
template<int LOGS, int NT>
__device__ __forceinline__ void radix4_stage(const float2* __restrict__ X,
                                             float2* __restrict__ Y,
                                             const float2* __restrict__ w512x,
                                             int tid) {
    const int s = 1 << LOGS;
    for (int t = tid; t < 640; t += NT) {
        int sub = t >> 7, r = t & 127;
        int base = sub << 9;
        int q = r & (s - 1);
        int ps = r - q;                         // p'*s
        float2 x0 = X[swz(base + r)];
        float2 x1 = X[swz(base + r + 128)];
        float2 x2 = X[swz(base + r + 256)];
        float2 x3 = X[swz(base + r + 384)];
        float A0r = x0.x + x2.x, A0i = x0.y + x2.y;
        float B0r = x1.x + x3.x, B0i = x1.y + x3.y;
        float A1r = x0.x - x2.x, A1i = x0.y - x2.y;
        float B1r = x1.x - x3.x, B1i = x1.y - x3.y;
        float2 w1 = w512x[ps];                  // e^{-2pi i ps/512}
        float w2r = w1.x * w1.x - w1.y * w1.y;  // w1^2
        float w2i = 2.0f * w1.x * w1.y;
        float w3r = w2r * w1.x - w2i * w1.y;    // w1^3
        float w3i = w2r * w1.y + w2i * w1.x;
        float u1r = A1r + B1i, u1i = A1i - B1r; // A1 + (-i)B1
        float u2r = A0r - B0r, u2i = A0i - B0i;
        float u3r = A1r - B1i, u3i = A1i + B1r; // A1 + i B1
        int ob = base + q + 4 * ps;
        Y[swz(ob)]         = make_float2(A0r + B0r, A0i + B0i);
        Y[swz(ob + s)]     = make_float2(u1r * w1.x - u1i * w1.y,
                                         u1r * w1.y + u1i * w1.x);
        Y[swz(ob + 2 * s)] = make_float2(u2r * w2r - u2i * w2i,
                                         u2r * w2i + u2i * w2r);
        Y[swz(ob + 3 * s)] = make_float2(u3r * w3r - u3i * w3i,
                                         u3r * w3i + u3i * w3r);
    }
}

// Requires NT == 512 (thread tid owns n2 = tid in the radix-5 stage).
// INPUT IN REGISTERS: x[m] = signal[m*512 + tid].
// tw[k1-1] = e^{-2pi i * k1*tid / 2560}, precomputed once per block.
// Output: bufA[k1*512+k2] = DFT[k1 + 5*k2].
template<int NT>
__device__ void fft2560(const float2* x, float2* bufA, float2* bufB,
                        const float2* w512x, const float2* tw, int tid) {
    {
        const float w5r[5] = { 1.f,  0.30901699437494742f, -0.80901699437494742f,
                              -0.80901699437494742f,  0.30901699437494742f };
        const float w5i[5] = { 0.f, -0.95105651629515357f, -0.58778525229247312f,
                               0.58778525229247312f,  0.95105651629515357f };
#pragma unroll
        for (int k1 = 0; k1 < 5; k1++) {
            float ar = 0.f, ai = 0.f;
#pragma unroll
            for (int n1 = 0; n1 < 5; n1++) {
                int m = (n1 * k1) % 5;
                ar += x[n1].x * w5r[m] - x[n1].y * w5i[m];
                ai += x[n1].x * w5i[m] + x[n1].y * w5r[m];
            }
            if (k1 == 0) {
                bufB[swz(tid)] = make_float2(ar, ai);
            } else {
                float2 w = tw[k1 - 1];
                bufB[swz(k1 * 512 + tid)] =
                    make_float2(ar * w.x - ai * w.y, ar * w.y + ai * w.x);
            }
        }
    }
    __syncthreads();    // publish radix-5 writes; also fences prev-col bufA reads
    radix4_stage<0, NT>(bufB, bufA, w512x, tid); __syncthreads();
    radix4_stage<2, NT>(bufA, bufB, w512x, tid); __syncthreads();
    radix4_stage<4, NT>(bufB, bufA, w512x, tid); __syncthreads();
    radix4_stage<6, NT>(bufA, bufB, w512x, tid); __syncthreads();
    // final radix-2 (s=256, twiddle = 1)
    for (int t = tid; t < 1280; t += NT) {
        int sub = t >> 8, q = t & 255;
        int base = sub << 9;
        float2 a = bufB[swz(base + q)];
        float2 b = bufB[swz(base + q + 256)];
        bufA[swz(base + q)]       = make_float2(a.x + b.x, a.y + b.y);
        bufA[swz(base + q + 256)] = make_float2(a.x - b.x, a.y - b.y);
    }
    __syncthreads();    // publish bufA before epilogue reads; fences bufB reuse
}

// one workgroup (512 threads) per (DGRP-channel group, b)
__global__ __launch_bounds__(FFT_NT) void fft_fwd_kernel(
    const float* __restrict__ qt, const float* __restrict__ kt, float* __restrict__ Z)
{
    __shared__ float2 bufA[SEQ];
    __shared__ float2 bufB[SEQ];
    __shared__ float2 w512x[512];
    int d0 = blockIdx.x * DGRP;
    int b = blockIdx.y;
    int tid = threadIdx.x;
    {
        float sn, cs;
        sincosf(-6.283185307179586f * (float)tid / 512.0f, &sn, &cs);
        w512x[tid] = make_float2(cs, sn);
    }
    // radix-5 twiddles depend only on (k1, n2=tid): hoist to registers, once.
    float2 tw[4];
#pragma unroll
    for (int k1 = 1; k1 <= 4; k1++) {
        float sn, cs;
        sincosf(-2.4543692606170259e-3f * (float)(k1 * tid), &sn, &cs);
        tw[k1 - 1] = make_float2(cs, sn);
    }
    float accR[5], accI[5];
#pragma unroll
    for (int j = 0; j < 5; j++) { accR[j] = 0.f; accI[j] = 0.f; }

    for (int col = 0; col < DGRP; col++) {
        const float* qcol = qt + (size_t)(d0 + col) * MROWS + (size_t)b * SEQ;
        const float* kcol = kt + (size_t)(d0 + col) * MROWS + (size_t)b * SEQ;
        // direct register load (same elements the radix-5 stage consumes)
        float2 x[5];
#pragma unroll
        for (int m = 0; m < 5; m++)
            x[m] = make_float2(qcol[m * 512 + tid], kcol[m * 512 + tid]);
        fft2560<FFT_NT>(x, bufA, bufB, w512x, tw, tid);
#pragma unroll
        for (int j = 0; j < 5; j++) {
            int f = tid + FFT_NT * j;
            int fpos = (f % 5) * 512 + (f / 5);
            int g = f ? (SEQ - f) : 0;
            int gpos = (g % 5) * 512 + (g / 5);
            float2 Z1 = bufA[swz(fpos)], Z2 = bufA[swz(gpos)];
            accR[j] += 0.5f * (Z1.x * Z2.y + Z1.y * Z2.x);            // Im(Z1*Z2)/2
            accI[j] += 0.25f * ((Z1.x * Z1.x + Z1.y * Z1.y)
                              - (Z2.x * Z2.x + Z2.y * Z2.y));         // (|Z1|^2-|Z2|^2)/4
        }
    }
#pragma unroll
    for (int j = 0; j < 5; j++) {
        int f = tid + FFT_NT * j;
        int fpos = (f % 5) * 512 + (f / 5);
        atomicAdd(&Z[((size_t)b * SEQ + fpos) * 2 + 0], accR[j]);
        atomicAdd(&Z[((size_t)b * SEQ + fpos) * 2 + 1], accI[j]);
    }
}

__global__ __launch_bounds__(FFT_NT) void fft_inv_kernel(
    const float* __restrict__ Z, float* __restrict__ mc)
{
    __shared__ float2 bufA[SEQ];
    __shared__ float2 bufB[SEQ];
    __shared__ float2 w512x[512];
    int b = blockIdx.x;
    int tid = threadIdx.x;
    {
        float sn, cs;
        sincosf(-6.283185307179586f * (float)tid / 512.0f, &sn, &cs);
        w512x[tid] = make_float2(cs, sn);
    }
    float2 tw[4];
#pragma unroll
    for (int k1 = 1; k1 <= 4; k1++) {
        float sn, cs;
        sincosf(-2.4543692606170259e-3f * (float)(k1 * tid), &sn, &cs);
        tw[k1 - 1] = make_float2(cs, sn);
    }
    // direct register load with the same index map the loader used
    float2 x[5];
#pragma unroll
    for (int m = 0; m < 5; m++) {
        int i = m * 512 + tid;
        int k1 = i % 5, k2 = i / 5;
        float zr = Z[((size_t)b * SEQ + k1 * 512 + k2) * 2 + 0];
        float zi = Z[((size_t)b * SEQ + k1 * 512 + k2) * 2 + 1];
        x[m] = make_float2(zr, -zi);
    }
    fft2560<FFT_NT>(x, bufA, bufB, w512x, tw, tid);
    const float scale = 1.0f / (2560.0f * 512.0f);
    for (int j = tid; j < SEQ; j += FFT_NT) {
        int k1 = j >> 9, k2 = j & 511;
        mc[(size_t)b * SEQ + k1 + 5 * k2] = bufA[swz(j)].x * scale;
    }
}

// ---------------- top-7 + softmax per batch ----------------
__global__ __launch_bounds__(256) void topk_kernel(
    const float* __restrict__ mc, float* __restrict__ wts, int* __restrict__ dels)
{
    __shared__ float cv[SEQ];
    __shared__ float rv[256];
    __shared__ int   ri[256];
    __shared__ float topv[TOPK];
    __shared__ int   topi[TOPK];
    int b = blockIdx.x, tid = threadIdx.x;
    for (int i = tid; i < SEQ; i += 256) cv[i] = mc[(size_t)b * SEQ + i];
    __syncthreads();
    for (int it = 0; it < TOPK; it++) {
        float bv = -2e30f; int bi = 1 << 30;
        for (int i = tid; i < SEQ; i += 256) {
            float v = cv[i];
            if (v > bv || (v == bv && i < bi)) { bv = v; bi = i; }
        }
        rv[tid] = bv; ri[tid] = bi;
        __syncthreads();
        for (int off = 128; off > 0; off >>= 1) {
            if (tid < off) {
                float v2 = rv[tid + off]; int i2 = ri[tid + off];
                if (v2 > rv[tid] || (v2 == rv[tid] && i2 < ri[tid])) {
                    rv[tid] = v2; ri[tid] = i2;
                }
            }
            __syncthreads();
        }
        if (tid == 0) { topv[it] = rv[0]; topi[it] = ri[0]; cv[ri[0]] = -1e30f; }
        __syncthreads();
    }
    if (tid == 0) {
        float mx = topv[0];
        float e[TOPK], ssum = 0.f;
        for (int i = 0; i < TOPK; i++) { e[i] = expf(topv[i] - mx); ssum += e[i]; }
        for (int i = 0; i < TOPK; i++) {
            wts[b * TOPK + i] = e[i] / ssum;
            dels[b * TOPK + i] = topi[i];
        }
    }
}

// ------- fused delay aggregation + bias + residual (float4 vectorized) -------
__global__ void agg_res_kernel(const float* __restrict__ u, const float* __restrict__ x,
                               const float* __restrict__ cb,
                               const float* __restrict__ wts, const int* __restrict__ dels,
                               float* __restrict__ x1) {
    size_t i4 = ((size_t)blockIdx.x * 256 + threadIdx.x) * 4;
    if (i4 >= SD) return;
    int d = (int)(i4 & (DMODEL - 1));
    size_t r = i4 >> 9;
    int s = (int)(r % SEQ);
    int b = (int)(r / SEQ);
    float4 xx = *(const float4*)(x + i4);
    float4 cc = *(const float4*)(cb + d);
    float a0 = cc.x + xx.x, a1 = cc.y + xx.y, a2 = cc.z + xx.z, a3 = cc.w + xx.w;
    const float* ub = u + (size_t)b * SEQ * DMODEL + d;
#pragma unroll
    for (int i = 0; i < TOPK; i++) {
        int del = dels[b * TOPK + i];
        float w = wts[b * TOPK + i];
        int ss = s + del; if (ss >= SEQ) ss -= SEQ;
        float4 uu = *(const float4*)(ub + (size_t)ss * DMODEL);
        a0 += w * uu.x; a1 += w * uu.y; a2 += w * uu.z; a3 += w * uu.w;
    }
    *(float4*)(x1 + i4) = make_float4(a0, a1, a2, a3);
}

// --------- x - moving_avg(x): running-window (r5/r7 proven scalar form) ------
// TLP-fed: 640 blocks x 256 threads; serial window update per thread.
#define MA_MODE_PLAIN 0
#define MA_MODE_BF    1
#define MA_MODE_SPLIT 2
template<int MODE>
__device__ __forceinline__ void ma_run_body(
    const float* __restrict__ x, float* __restrict__ out,
    unsigned short* __restrict__ o1, unsigned short* __restrict__ o2)
{
    int tid = threadIdx.x;
    int s0 = blockIdx.x * 128;
    int d  = blockIdx.y * 256 + tid;
    int b  = blockIdx.z;
    const float* xb = x + (size_t)b * SEQ * DMODEL + d;
    float sum = 0.f;
#pragma unroll
    for (int j = -12; j <= 12; j++) {
        int ss = s0 + j;
        ss = ss < 0 ? 0 : (ss > SEQ - 1 ? SEQ - 1 : ss);
        sum += xb[(size_t)ss * DMODEL];
    }
    for (int s = s0; s < s0 + 128; s++) {
        float v = xb[(size_t)s * DMODEL] - sum * (1.0f / 25.0f);
        size_t o = ((size_t)b * SEQ + s) * DMODEL + d;
        out[o] = v;
        if (MODE == MA_MODE_BF) {
            o1[o] = f2bf(v);
        } else if (MODE == MA_MODE_SPLIT) {
            unsigned short h = f2bf(v);
            o1[o] = h;
            o2[o] = f2bf(v - bf2f(h));
        }
        int add = s + 13; if (add > SEQ - 1) add = SEQ - 1;
        int sub = s - 12; if (sub < 0) sub = 0;
        sum += xb[(size_t)add * DMODEL] - xb[(size_t)sub * DMODEL];
    }
}
__global__ __launch_bounds__(256) void ma_sub_kernel(
    const float* __restrict__ x, float* __restrict__ out) {
    ma_run_body<MA_MODE_PLAIN>(x, out, nullptr, nullptr);
}
__global__ __launch_bounds__(256) void ma_sub_bf_kernel(
    const float* __restrict__ x, float* __restrict__ out,
    unsigned short* __restrict__ obf) {
    ma_run_body<MA_MODE_BF>(x, out, obf, nullptr);
}
__global__ __launch_bounds__(256) void ma_sub_split_kernel(
    const float* __restrict__ x, float* __restrict__ out,
    unsigned short* __restrict__ hi, unsigned short* __restrict__ lo) {
    ma_run_body<MA_MODE_SPLIT>(x, out, hi, lo);
}

// ---------------- layernorm over last dim ----------------
__global__ __launch_bounds__(256) void ln_kernel(
    const float* __restrict__ x, const float* __restrict__ g,
    const float* __restrict__ be, float* __restrict__ xh)
{
    int row = blockIdx.x;
    int tid = threadIdx.x;
    __shared__ float red[256];
    const float* xr = x + (size_t)row * DMODEL;
    float v0 = xr[tid], v1 = xr[tid + 256];
    red[tid] = v0 + v1;
    __syncthreads();
    for (int off = 128; off > 0; off >>= 1) {
        if (tid < off) red[tid] += red[tid + off];
        __syncthreads();
    }
    float mu = red[0] / (float)DMODEL;
    __syncthreads();
    float d0 = v0 - mu, d1 = v1 - mu;
    red[tid] = d0 * d0 + d1 * d1;
    __syncthreads();
    for (int off = 128; off > 0; off >>= 1) {
        if (tid < off) red[tid] += red[tid + off];
        __syncthreads();
    }
    float inv = rsqrtf(red[0] / (float)DMODEL + 1e-5f);
    xh[(size_t)row * DMODEL + tid]       = d0 * inv * g[tid] + be[tid];
    xh[(size_t)row * DMODEL + tid + 256] = d1 * inv * g[tid + 256] + be[tid + 256];
}

// ------ per-(b,d) mean over sequence (float4 cols, atomic partials) ----------
__global__ __launch_bounds__(256) void colmean_kernel(
    const float* __restrict__ xh, float* __restrict__ cm) {
    int q = blockIdx.x * 256 + threadIdx.x;     // 0..2047, 4 cols each
    int idx = q * 4;                            // (b,d) base
    int d = idx & (DMODEL - 1), b = idx >> 9;
    int s0 = blockIdx.y * 128;
    const float* xb = xh + (size_t)b * SEQ * DMODEL + d;
    float a0 = 0.f, a1 = 0.f, a2 = 0.f, a3 = 0.f;
    for (int s = s0; s < s0 + 128; s++) {
        float4 v = *(const float4*)(xb + (size_t)s * DMODEL);
        a0 += v.x; a1 += v.y; a2 += v.z; a3 += v.w;
    }
    atomicAdd(&cm[idx + 0], a0 * (1.0f / (float)SEQ));
    atomicAdd(&cm[idx + 1], a1 * (1.0f / (float)SEQ));
    atomicAdd(&cm[idx + 2], a2 * (1.0f / (float)SEQ));
    atomicAdd(&cm[idx + 3], a3 * (1.0f / (float)SEQ));
}

__global__ __launch_bounds__(256) void final_kernel(
    const float* __restrict__ xh, const float* __restrict__ cm,
    const float* __restrict__ Wp, const float* __restrict__ bp,
    float* __restrict__ out)
{
    int b = blockIdx.y, chunk = blockIdx.x;
    int tid = threadIdx.x;
    const size_t per = (size_t)SEQ * DMODEL / 64;   // 20480, %1024 == 0
    size_t start = (size_t)chunk * per;
    float acc = 0.f;
    for (size_t i = start + tid * 4; i < start + per; i += 1024) {
        int d = (int)(i & (DMODEL - 1));
        float4 v = *(const float4*)(xh + (size_t)b * SEQ * DMODEL + i);
        float4 c = *(const float4*)(cm + b * DMODEL + d);
        float4 w = *(const float4*)(Wp + i);
        acc += gelu_f(v.x - c.x) * w.x + gelu_f(v.y - c.y) * w.y
             + gelu_f(v.z - c.z) * w.z + gelu_f(v.w - c.w) * w.w;
    }
    __shared__ float red[256];
    red[tid] = acc;
    __syncthreads();
    for (int off = 128; off > 0; off >>= 1) {
        if (tid < off) red[tid] += red[tid + off];
        __syncthreads();
    }
    if (tid == 0) {
        atomicAdd(&out[b], red[0]);
        if (chunk == 0) atomicAdd(&out[b], bp[0]);
    }
}

// ---------------- orchestration: 3-buffer rotation, NO input/output aliasing ----
extern "C" void kernel_launch(void* const* d_in, const int* in_sizes, int n_in,
                              void* d_out, int out_size, void* d_ws, size_t ws_size,
                              hipStream_t stream) {
    const float* data  = (const float*)d_in[0];
    const float* mask  = (const float*)d_in[1];
    const float* Wemb  = (const float*)d_in[2];
    const float* Wq    = (const float*)d_in[3];
    const float* bq    = (const float*)d_in[4];
    const float* Wk    = (const float*)d_in[5];
    const float* bk    = (const float*)d_in[6];
    const float* Wv    = (const float*)d_in[7];
    const float* bv    = (const float*)d_in[8];
    const float* Wo    = (const float*)d_in[9];
    const float* bo    = (const float*)d_in[10];
    const float* Wc1   = (const float*)d_in[11];
    const float* Wc2   = (const float*)d_in[12];
    const float* gamma = (const float*)d_in[13];
    const float* beta  = (const float*)d_in[14];
    const float* Wp    = (const float*)d_in[15];
    const float* bp    = (const float*)d_in[16];
    float* out = (float*)d_out;

    float* buf0 = (float*)d_ws;
    float* buf1 = buf0 + SD;
    float* buf2 = buf1 + SD;

    unsigned short* WstkH = (unsigned short*)(buf2 + SD);   // 2*512*512 stacked q/k hi
    unsigned short* WstkL = WstkH + 2 * DMODEL * DMODEL;    // stacked q/k lo
    unsigned short* Wvot  = WstkL + 2 * DMODEL * DMODEL;    // bf16 [N][K] of Wv@Wo
    unsigned short* Wc1t  = Wvot + DMODEL * DMODEL;         // [2048][512]
    unsigned short* Wc2t  = Wc1t + (size_t)DMODEL * DFF;    // [512][2048]
    float* WvoF = (float*)(Wc2t + (size_t)DMODEL * DFF);    // fp32 Wv@Wo (512x512)
    float* CB   = WvoF + (size_t)DMODEL * DMODEL;           // cb = bv@Wo + bo
    float* Bstk = CB + DMODEL;                              // stacked q/k bias (1024)
    float* Zb = Bstk + 1024;
    float* MC = Zb + (size_t)BATCH * SEQ * 2;
    float* WT = MC + (size_t)BATCH * SEQ;
    int*   DL = (int*)(WT + BATCH * TOPK);
    float* CM = (float*)(DL + BATCH * TOPK);

    const int NB  = (int)((SD + 255) / 256);
    const int NB4 = (int)((SD / 4 + 255) / 256);
    dim3 gMA(SEQ / 128, 2, BATCH);              // (20, 2, 16) running-window MA

    float* X  = buf0;   // x fp32
    float* HL = buf1;   // hi/lo pool
    float* S  = buf2;   // scratch

    // embed + fused hi/lo split (vectorized): hi -> upper half of HL, lo -> lower
    embed_kernel<<<MROWS / 2, 256, 0, stream>>>(data, mask, Wemb, X,
                                                (unsigned short*)HL + SD,
                                                (unsigned short*)HL);

    // 1-D swizzled GEMM grids: blocks = gridM*gridN (gridM % 8 == 0)
    const int gSqBlocks = (MROWS / 128) * (DMODEL / 128);       // 320*4 = 1280
    const int gF1Blocks = (FFN_CHUNK / 128) * (DFF / 128);      // 160*16 = 2560
    const int gF2Blocks = (FFN_CHUNK / 128) * (DMODEL / 128);   // 160*4 = 640

    for (int l = 0; l < NLAYERS; l++) {
        const float* wq = Wq + (size_t)l * DMODEL * DMODEL;
        const float* wk = Wk + (size_t)l * DMODEL * DMODEL;
        const float* wv = Wv + (size_t)l * DMODEL * DMODEL;
        const float* wo = Wo + (size_t)l * DMODEL * DMODEL;
        const float* bqL = bq + (size_t)l * DMODEL;
        const float* bkL = bk + (size_t)l * DMODEL;
        const float* bvL = bv + (size_t)l * DMODEL;
        const float* boL = bo + (size_t)l * DMODEL;
        const float* wc1 = Wc1 + (size_t)l * DMODEL * DFF;
        const float* wc2 = Wc2 + (size_t)l * DFF * DMODEL;

        unsigned short* Lbf = (unsigned short*)HL;      // x_lo (lower half)
        unsigned short* Hbf = Lbf + SD;                 // x_hi (upper half)
        float* qtf = S;                                 // q cols (MROWS*256)
        float* ktf = S + (size_t)MROWS * CHUNK_D;       // k cols

        dim3 gT(DMODEL / 32, DMODEL / 32);
        transpose_split_stk_kernel<<<gT, 256, 0, stream>>>(wq, WstkH, WstkL, 0);
        transpose_split_stk_kernel<<<gT, 256, 0, stream>>>(wk, WstkH, WstkL, 1);
        stack_bias_kernel<<<4, 256, 0, stream>>>(bqL, bkL, Bstk);
        wvo_kernel<<<DMODEL, 256, 0, stream>>>(wv, wo, WvoF);
        transpose_bf16_kernel<<<gT, 256, 0, stream>>>(WvoF, Wvot, DMODEL, DMODEL);
        cbias_kernel<<<2, 256, 0, stream>>>(bvL, wo, boL, CB);
        transpose_bf16_kernel<<<dim3(DFF / 32, DMODEL / 32), 256, 0, stream>>>(wc1, Wc1t, DMODEL, DFF);
        transpose_bf16_kernel<<<dim3(DMODEL / 32, DFF / 32), 256, 0, stream>>>(wc2, Wc2t, DFF, DMODEL);

        // q&k stacked: one split GEMM per 256-col chunk into S (N=512 covers both)
        hipMemsetAsync(Zb, 0, (size_t)BATCH * SEQ * 2 * sizeof(float), stream);
        for (int c = 0; c < DMODEL / CHUNK_D; c++) {
            gemm_qk_split_kernel<<<gSqBlocks, 256, 0, stream>>>(
                Hbf, Lbf, WstkH + (size_t)c * 512 * DMODEL,
                WstkL + (size_t)c * 512 * DMODEL, Bstk + c * 512,
                S, MROWS, DMODEL, DMODEL / 128);
            fft_fwd_kernel<<<dim3(CHUNK_D / DGRP, BATCH), FFT_NT, 0, stream>>>(qtf, ktf, Zb);
        }
        fft_inv_kernel<<<BATCH, FFT_NT, 0, stream>>>(Zb, MC);
        topk_kernel<<<BATCH, 256, 0, stream>>>(MC, WT, DL);

        // u = x@(Wv@Wo) -> S fp32 (qtf/ktf dead)
        gemm_mfma_kernel<<<gSqBlocks, 256, 0, stream>>>(Hbf, Wvot, nullptr, nullptr, S,
                                                        MROWS, DMODEL, DMODEL, 0, 0,
                                                        DMODEL / 128);
        // x1 = sum w_i roll(u) + cb + x -> HL as fp32 (x hi/lo dead)
        agg_res_kernel<<<NB4, 256, 0, stream>>>(S, X, CB, WT, DL, HL);
        // x2 = x1 - MA(x1): fp32 -> X (x dead), bf16 -> S (u dead). No aliasing.
        ma_sub_bf_kernel<<<gMA, 256, 0, stream>>>(HL, X, (unsigned short*)S);
        // FFN in 2 row-chunks: gelu bf16 fills HL exactly (x1 dead);
        // z in-place over X (res==out, same-index).
        for (int c = 0; c < MROWS / FFN_CHUNK; c++) {
            const unsigned short* x2c = (unsigned short*)S + (size_t)c * FFN_CHUNK * DMODEL;
            float* xz = X + (size_t)c * FFN_CHUNK * DMODEL;
            gemm_mfma_kernel<<<gF1Blocks, 256, 0, stream>>>(x2c, Wc1t, nullptr, nullptr,
                                                            (unsigned short*)HL,
                                                            FFN_CHUNK, DFF, DMODEL, 1, 1,
                                                            DFF / 128);
            gemm_mfma_kernel<<<gF2Blocks, 256, 0, stream>>>((unsigned short*)HL, Wc2t,
                                                            nullptr, xz, xz,
                                                            FFN_CHUNK, DMODEL, DFF, 0, 0,
                                                            DMODEL / 128);
        }
        // h = z - MA(z): z in X -> h fp32 -> S (+ hi/lo -> HL if another layer)
        if (l + 1 < NLAYERS)
            ma_sub_split_kernel<<<gMA, 256, 0, stream>>>(
                X, S, (unsigned short*)HL + SD, (unsigned short*)HL);
        else
            ma_sub_kernel<<<gMA, 256, 0, stream>>>(X, S);
        // rotate: next layer's x is in S
        float* tmp = X; X = S; S = tmp;
    }

    // final h is in X; use HL for xh
    ln_kernel<<<MROWS, 256, 0, stream>>>(X, gamma, beta, HL);
    hipMemsetAsync(CM, 0, (size_t)BATCH * DMODEL * sizeof(float), stream);
    colmean_kernel<<<dim3(8, 20), 256, 0, stream>>>(HL, CM);
    hipMemsetAsync(out, 0, (size_t)out_size * sizeof(float), stream);
    final_kernel<<<dim3(64, BATCH), 256, 0, stream>>>(HL, CM, Wp, bp, out);
}

// Round 15
// 1959.482 us; speedup vs baseline: 1.0761x; 1.0221x over previous
//
#include <hip/hip_runtime.h>
#include <math.h>

// ---------------- problem constants ----------------
#define BATCH 16
#define L_CYC 20
#define CDL 128
#define SEQ 2560            // L_CYC * CDL
#define ENC_IN 3
#define DMODEL 512
#define DFF 2048
#define NLAYERS 2
#define TOPK 7
#define MROWS (BATCH*SEQ)   // 40960
#define SD ((size_t)BATCH * SEQ * DMODEL)   // 20,971,520
#define FFN_CHUNK 20480     // 2 chunks; 20480*2048 ushorts == SD*4 bytes exactly
#define CHUNK_D 256         // q/k column-chunk width
#define DGRP 8              // FFT channels per workgroup (proven; 4 regressed r6)
#define FFT_NT 512          // threads per FFT block (round-15 proven)

typedef short bf16x8 __attribute__((ext_vector_type(8)));
typedef float f32x4 __attribute__((ext_vector_type(4)));

// fast gelu: A&S 7.1.26 erf (|err| <= 1.5e-7), hw exp; ~14 VALU ops vs ~30 libm
__device__ __forceinline__ float gelu_f(float x) {
    float z = x * 0.70710678118654752f;
    float az = fabsf(z);
    float t = __builtin_amdgcn_rcpf(1.0f + 0.3275911f * az);
    float poly = t * (0.254829592f + t * (-0.284496736f + t * (1.421413741f
               + t * (-1.453152027f + t * 1.061405429f))));
    float e = __expf(-az * az);
    float erfv = 1.0f - poly * e;
    erfv = copysignf(erfv, z);
    return 0.5f * x * (1.0f + erfv);
}
__device__ __forceinline__ unsigned short f2bf(float f) {
    unsigned int u = __float_as_uint(f);
    u += 0x7fff + ((u >> 16) & 1);          // RNE
    return (unsigned short)(u >> 16);
}
__device__ __forceinline__ float bf2f(unsigned short h) {
    return __uint_as_float(((unsigned int)h) << 16);
}
// XCD-aware swizzle: 1-D block id p -> (row-group g, n-tile n) with all G
// n-tiles of g on the same XCD (round-robin p%8). Requires gridM % 8 == 0.
__device__ __forceinline__ void xcd_map(int p, int G, int& g, int& n) {
    int a = p >> 3;
    n = a % G;
    g = (a / G) * 8 + (p & 7);
}
// async global->LDS, 16B per lane; LDS dest is wave-uniform base + lane*16.
__device__ __forceinline__ void gload16(const unsigned short* g, unsigned short* l) {
    typedef unsigned int u32;
    __builtin_amdgcn_global_load_lds(
        (const __attribute__((address_space(1))) u32*)g,
        (__attribute__((address_space(3))) u32*)l, 16, 0, 0);
}

// -------- embed: mask + reshape + circular conv1d(k=3) + fused hi/lo split ----
// float4/ushort4 stores (r4 agg_res pattern): 2 rows/block, 4 cols/thread.
__global__ __launch_bounds__(256) void embed_kernel(
    const float* __restrict__ data, const float* __restrict__ mask,
    const float* __restrict__ Wemb, float* __restrict__ h,
    unsigned short* __restrict__ hi, unsigned short* __restrict__ lo) {
    __shared__ float xv[2][9];      // [local row][c*3 + t]
    int tid = threadIdx.x;
    size_t r0 = (size_t)blockIdx.x * 2;
    if (tid < 18) {
        int lr = tid / 9, k = tid % 9;
        int t = k / 3, c = k % 3;
        size_t r = r0 + lr;
        int s = (int)(r % SEQ);
        int b = (int)(r / SEQ);
        int u = s - 1 + t;
        if (u < 0) u += SEQ;
        if (u >= SEQ) u -= SEQ;
        int cyc = u >> 7, pos = u & 127;
        float mk = mask[b * L_CYC + cyc];
        xv[lr][c * 3 + t] = (mk == 0.f) ? 0.f
            : data[(((size_t)b * L_CYC + cyc) * ENC_IN + c) * CDL + pos];
    }
    __syncthreads();
    int lr = tid >> 7;
    int dm = (tid & 127) * 4;
    size_t idx = (r0 + lr) * DMODEL + dm;
    float a[4];
#pragma unroll
    for (int q = 0; q < 4; q++) {
        float acc = 0.f;
#pragma unroll
        for (int j = 0; j < 9; j++) acc += xv[lr][j] * Wemb[(dm + q) * 9 + j];
        a[q] = acc;
    }
    *(float4*)(h + idx) = make_float4(a[0], a[1], a[2], a[3]);
    ushort4 hv = make_ushort4(f2bf(a[0]), f2bf(a[1]), f2bf(a[2]), f2bf(a[3]));
    *(ushort4*)(hi + idx) = hv;
    ushort4 lv = make_ushort4(f2bf(a[0] - bf2f(hv.x)), f2bf(a[1] - bf2f(hv.y)),
                              f2bf(a[2] - bf2f(hv.z)), f2bf(a[3] - bf2f(hv.w)));
    *(ushort4*)(lo + idx) = lv;
}

// ---------------- transpose W[K][N] fp32 -> Wt[N][K] bf16 ----------------
__global__ __launch_bounds__(256) void transpose_bf16_kernel(
    const float* __restrict__ W, unsigned short* __restrict__ Wt, int K, int N) {
    __shared__ float t[32][33];
    int n0 = blockIdx.x * 32, k0 = blockIdx.y * 32;
    int c = threadIdx.x & 31, r = threadIdx.x >> 5;   // r: 0..7
    for (int i = 0; i < 4; i++)
        t[r + i * 8][c] = W[(size_t)(k0 + r + i * 8) * N + n0 + c];
    __syncthreads();
    for (int i = 0; i < 4; i++)
        Wt[(size_t)(n0 + r + i * 8) * K + k0 + c] = f2bf(t[c][r + i * 8]);
}

// ---- transpose 512x512 W -> STACKED hi/lo bf16: q/k interleaved per 256-chunk ----
__global__ __launch_bounds__(256) void transpose_split_stk_kernel(
    const float* __restrict__ W, unsigned short* __restrict__ WtH,
    unsigned short* __restrict__ WtL, int which) {
    __shared__ float t[32][33];
    int n0 = blockIdx.x * 32, k0 = blockIdx.y * 32;
    int c = threadIdx.x & 31, r = threadIdx.x >> 5;
    for (int i = 0; i < 4; i++)
        t[r + i * 8][c] = W[(size_t)(k0 + r + i * 8) * DMODEL + n0 + c];
    __syncthreads();
    for (int i = 0; i < 4; i++) {
        int n = n0 + r + i * 8;
        int row = (n & 255) + ((n >> 8) * 512) + which * 256;
        float v = t[c][r + i * 8];
        unsigned short h = f2bf(v);
        size_t o = (size_t)row * DMODEL + k0 + c;
        WtH[o] = h;
        WtL[o] = f2bf(v - bf2f(h));
    }
}

// ---------------- stacked bias ----------------
__global__ void stack_bias_kernel(const float* __restrict__ bq,
                                  const float* __restrict__ bk, float* __restrict__ bstk) {
    int i = blockIdx.x * 256 + threadIdx.x;     // 0..1023
    if (i >= 1024) return;
    int c = i >> 9, j = i & 511;
    bstk[i] = (j < 256) ? bq[c * 256 + j] : bk[c * 256 + (j - 256)];
}

// ---------------- Wvo = Wv @ Wo (fp32, per layer; 512 blocks) ----------------
__global__ __launch_bounds__(256) void wvo_kernel(
    const float* __restrict__ Wv, const float* __restrict__ Wo,
    float* __restrict__ Wvo) {
    __shared__ float row[DMODEL];
    int k = blockIdx.x;
    int tid = threadIdx.x;
    for (int j = tid; j < DMODEL; j += 256) row[j] = Wv[(size_t)k * DMODEL + j];
    __syncthreads();
    float a0 = 0.f, a1 = 0.f;
    for (int j = 0; j < DMODEL; j++) {
        float wv = row[j];
        a0 += wv * Wo[(size_t)j * DMODEL + tid];
        a1 += wv * Wo[(size_t)j * DMODEL + tid + 256];
    }
    Wvo[(size_t)k * DMODEL + tid] = a0;
    Wvo[(size_t)k * DMODEL + tid + 256] = a1;
}

// ---------------- cb = bv @ Wo + bo ----------------
__global__ void cbias_kernel(const float* __restrict__ bv, const float* __restrict__ Wo,
                             const float* __restrict__ bo, float* __restrict__ cb) {
    int n = blockIdx.x * 256 + threadIdx.x;
    if (n >= DMODEL) return;
    float acc = bo[n];
    for (int j = 0; j < DMODEL; j++) acc += bv[j] * Wo[(size_t)j * DMODEL + n];
    cb[n] = acc;
}

// ------ bf16 MFMA GEMM: dbuf BK=32 @ 32KB total (occupancy-neutral vs the
// BK=64 single-buffer) + reads-first prefetch + sched_barrier(0).
// The untested cell of the pipelining matrix: r3 failed via compiler vmcnt(0)
// before ds_reads (prefetch-first order); r6 failed via 64KB occupancy loss.
// Here: fragments read FIRST, then prefetch issued, then MFMA; the end-of-step
// vmcnt(0) waits on loads that had the whole MFMA phase to fly.
// Slot swizzle = qk kernel's proven scheme (9 rounds of correctness).
#define BK 32
__global__ __launch_bounds__(256) void gemm_mfma_kernel(
    const unsigned short* __restrict__ A, const unsigned short* __restrict__ Wt,
    const float* __restrict__ bias, const float* res,
    void* Cout, int M, int N, int K, int act, int outMode, int gridN)
{
    __shared__ unsigned short As[2][128 * 32];   // 2 x 8KB
    __shared__ unsigned short Bs[2][128 * 32];   // 2 x 8KB
    int tid = threadIdx.x;
    int wave = tid >> 6, lane = tid & 63;
    int wm = wave & 1, wn = wave >> 1;
    int gblk, nblk;
    xcd_map(blockIdx.x, gridN, gblk, nblk);
    int bm = gblk * 128, bn = nblk * 128;

    int lrs = lane >> 2;                                    // row within 16-row chunk
    int lk  = (((lane & 3) ^ ((lane >> 3) & 3))) * 8;       // pre-swizzled source col
    int j0 = wave * 2, j1 = wave * 2 + 1;
    const unsigned short* Ag0 = A  + (size_t)(bm + j0 * 16 + lrs) * K + lk;
    const unsigned short* Ag1 = A  + (size_t)(bm + j1 * 16 + lrs) * K + lk;
    const unsigned short* Bg0 = Wt + (size_t)(bn + j0 * 16 + lrs) * K + lk;
    const unsigned short* Bg1 = Wt + (size_t)(bn + j1 * 16 + lrs) * K + lk;

    f32x4 acc[4][4] = {};
    int frow = lane & 15;
    int fk = (((lane >> 4) ^ ((frow >> 1) & 3))) * 8;       // swizzled read slot
    int nst = K / BK;

    // prologue: stage tile 0 -> buf 0
    gload16(Ag0, &As[0][j0 * 512]);
    gload16(Ag1, &As[0][j1 * 512]);
    gload16(Bg0, &Bs[0][j0 * 512]);
    gload16(Bg1, &Bs[0][j1 * 512]);
    asm volatile("s_waitcnt vmcnt(0)" ::: "memory");
    __syncthreads();

    for (int t = 0; t < nst; ++t) {
        int cur = t & 1, nxt = cur ^ 1;
        // 1) ALL fragment ds_reads from buf[cur] FIRST (prevents the r3
        //    alias-conservative vmcnt(0)-before-reads failure mode)
        bf16x8 af[4], bfv[4];
#pragma unroll
        for (int mi = 0; mi < 4; mi++)
            af[mi] = *(const bf16x8*)&As[cur][(wm * 64 + mi * 16 + frow) * 32 + fk];
#pragma unroll
        for (int nj = 0; nj < 4; nj++)
            bfv[nj] = *(const bf16x8*)&Bs[cur][(wn * 64 + nj * 16 + frow) * 32 + fk];
        __builtin_amdgcn_sched_barrier(0);    // keep prefetch AFTER the reads
        // 2) prefetch next tile -> buf[nxt]; flies under the MFMAs below
        if (t + 1 < nst) {
            int k0 = (t + 1) * BK;
            gload16(Ag0 + k0, &As[nxt][j0 * 512]);
            gload16(Ag1 + k0, &As[nxt][j1 * 512]);
            gload16(Bg0 + k0, &Bs[nxt][j0 * 512]);
            gload16(Bg1 + k0, &Bs[nxt][j1 * 512]);
        }
        // 3) MFMA (compiler inserts counted lgkmcnt for the fragment reads)
#pragma unroll
        for (int mi = 0; mi < 4; mi++)
#pragma unroll
            for (int nj = 0; nj < 4; nj++)
                acc[mi][nj] = __builtin_amdgcn_mfma_f32_16x16x32_bf16(
                    af[mi], bfv[nj], acc[mi][nj], 0, 0, 0);
        // 4) drain prefetch (hidden under step 3), publish buf[nxt]
        asm volatile("s_waitcnt vmcnt(0)" ::: "memory");
        __syncthreads();
    }

    int lrow = (lane >> 4) * 4, lcol = lane & 15;
#pragma unroll
    for (int mi = 0; mi < 4; mi++) {
        int row0 = bm + wm * 64 + mi * 16 + lrow;
#pragma unroll
        for (int nj = 0; nj < 4; nj++) {
            int col = bn + wn * 64 + nj * 16 + lcol;
            float bv = bias ? bias[col] : 0.f;
            f32x4 v = acc[mi][nj];
#pragma unroll
            for (int r = 0; r < 4; r++) {
                int row = row0 + r;
                float x = v[r] + bv;
                if (res) x += res[(size_t)row * N + col];
                if (act == 1) x = gelu_f(x);
                if (outMode == 0) ((float*)Cout)[(size_t)row * N + col] = x;
                else              ((unsigned short*)Cout)[(size_t)row * N + col] = f2bf(x);
            }
        }
    }
}

// -- split-precision MFMA GEMM for q/k (BK=32 + T2 slot swizzle both sides) ---
// Output fp32 TRANSPOSED: Ct[col*M + row]. N=512 stacked covers q&k. gridN=4.
#define QBK 32
__global__ __launch_bounds__(256) void gemm_qk_split_kernel(
    const unsigned short* __restrict__ Ahi, const unsigned short* __restrict__ Alo,
    const unsigned short* __restrict__ Whi, const unsigned short* __restrict__ Wlo,
    const float* __restrict__ bias, float* __restrict__ Ct, int M, int K, int gridN)
{
    __shared__ unsigned short AsH[128 * 32];
    __shared__ unsigned short AsL[128 * 32];
    __shared__ unsigned short BsH[128 * 32];
    __shared__ unsigned short BsL[128 * 32];
    int tid = threadIdx.x;
    int wave = tid >> 6, lane = tid & 63;
    int wm = wave & 1, wn = wave >> 1;
    int gblk, nblk;
    xcd_map(blockIdx.x, gridN, gblk, nblk);
    int bm = gblk * 128, bn = nblk * 128;

    int lrs = lane >> 2;                                    // row within 16-row chunk
    int lk  = (((lane & 3) ^ ((lane >> 3) & 3))) * 8;       // pre-swizzled source col

    f32x4 acc[4][4] = {};
    int frow = lane & 15;
    int fk = (((lane >> 4) ^ ((frow >> 1) & 3))) * 8;       // swizzled read slot

    for (int k0 = 0; k0 < K; k0 += QBK) {
        __syncthreads();
#pragma unroll
        for (int i = 0; i < 2; i++) {
            int j = wave * 2 + i;
            int row = j * 16 + lrs;
            size_t oa = (size_t)(bm + row) * K + k0 + lk;
            size_t ob = (size_t)(bn + row) * K + k0 + lk;
            gload16(Ahi + oa, AsH + j * 512);
            gload16(Alo + oa, AsL + j * 512);
            gload16(Whi + ob, BsH + j * 512);
            gload16(Wlo + ob, BsL + j * 512);
        }
        asm volatile("s_waitcnt vmcnt(0)" ::: "memory");
        __syncthreads();
        bf16x8 afh[4], afl[4], bfh[4], bfl[4];
#pragma unroll
        for (int mi = 0; mi < 4; mi++) {
            int o = (wm * 64 + mi * 16 + frow) * 32 + fk;
            afh[mi] = *(const bf16x8*)&AsH[o];
            afl[mi] = *(const bf16x8*)&AsL[o];
        }
#pragma unroll
        for (int nj = 0; nj < 4; nj++) {
            int o = (wn * 64 + nj * 16 + frow) * 32 + fk;
            bfh[nj] = *(const bf16x8*)&BsH[o];
            bfl[nj] = *(const bf16x8*)&BsL[o];
        }
#pragma unroll
        for (int mi = 0; mi < 4; mi++)
#pragma unroll
            for (int nj = 0; nj < 4; nj++) {
                acc[mi][nj] = __builtin_amdgcn_mfma_f32_16x16x32_bf16(
                    afh[mi], bfh[nj], acc[mi][nj], 0, 0, 0);
                acc[mi][nj] = __builtin_amdgcn_mfma_f32_16x16x32_bf16(
                    afh[mi], bfl[nj], acc[mi][nj], 0, 0, 0);
                acc[mi][nj] = __builtin_amdgcn_mfma_f32_16x16x32_bf16(
                    afl[mi], bfh[nj], acc[mi][nj], 0, 0, 0);
            }
    }

    int lrow = (lane >> 4) * 4, lcol = lane & 15;
#pragma unroll
    for (int mi = 0; mi < 4; mi++) {
        int row0 = bm + wm * 64 + mi * 16 + lrow;
#pragma unroll
        for (int nj = 0; nj < 4; nj++) {
            int col = bn + wn * 64 + nj * 16 + lcol;
            float bv = bias ? bias[col] : 0.f;
            f32x4 v = acc[mi][nj];
#pragma unroll
            for (int r = 0; r < 4; r++)
                Ct[(size_t)col * M + row0 + r] = v[r] + bv;
        }
    }
}

// ---------------- 2560-pt FFT (radix-5 + reg twiddle + 4x radix-4 + radix-2) --
// LDS index swizzle: kills Stockham stride-write bank conflicts. Bijective
// (upper bits unchanged), applied to EVERY bufA/bufB access.
__device__ __forceinline__ int swz(int a) { return a ^ ((a >> 4) & 15); }

// One radix-4 Stockham stage, S = 1<<LOGS in {1,4,16,64}.
template<int LOGS, int NT>
__device__ __forceinline__ void radix4_stage(const float2* __restrict__ X,
                                             float2* __restrict__ Y,
                                             const float2* __restrict__ w512x,
                                             int tid) {
    const int s = 1 << LOGS;
    for (int t = tid; t < 640; t += NT) {
        int sub = t >> 7, r = t & 127;
        int base = sub << 9;
        int q = r & (s - 1);
        int ps = r - q;                         // p'*s
        float2 x0 = X[swz(base + r)];
        float2 x1 = X[swz(base + r + 128)];
        float2 x2 = X[swz(base + r + 256)];
        float2 x3 = X[swz(base + r + 384)];
        float A0r = x0.x + x2.x, A0i = x0.y + x2.y;
        float B0r = x1.x + x3.x, B0i = x1.y + x3.y;
        float A1r = x0.x - x2.x, A1i = x0.y - x2.y;
        float B1r = x1.x - x3.x, B1i = x1.y - x3.y;
        float2 w1 = w512x[ps];                  // e^{-2pi i ps/512}
        float w2r = w1.x * w1.x - w1.y * w1.y;  // w1^2
        float w2i = 2.0f * w1.x * w1.y;
        float w3r = w2r * w1.x - w2i * w1.y;    // w1^3
        float w3i = w2r * w1.y + w2i * w1.x;
        float u1r = A1r + B1i, u1i = A1i - B1r; // A1 + (-i)B1
        float u2r = A0r - B0r, u2i = A0i - B0i;
        float u3r = A1r - B1i, u3i = A1i + B1r; // A1 + i B1
        int ob = base + q + 4 * ps;
        Y[swz(ob)]         = make_float2(A0r + B0r, A0i + B0i);
        Y[swz(ob + s)]     = make_float2(u1r * w1.x - u1i * w1.y,
                                         u1r * w1.y + u1i * w1.x);
        Y[swz(ob + 2 * s)] = make_float2(u2r * w2r - u2i * w2i,
                                         u2r * w2i + u2i * w2r);
        Y[swz(ob + 3 * s)] = make_float2(u3r * w3r - u3i * w3i,
                                         u3r * w3i + u3i * w3r);
    }
}

// Requires NT == 512 (thread tid owns n2 = tid in the radix-5 stage).
// INPUT IN REGISTERS: x[m] = signal[m*512 + tid].
// tw[k1-1] = e^{-2pi i * k1*tid / 2560}, precomputed once per block.
// Output: bufA[k1*512+k2] = DFT[k1 + 5*k2].
template<int NT>
__device__ void fft2560(const float2* x, float2* bufA, float2* bufB,
                        const float2* w512x, const float2* tw, int tid) {
    {
        const float w5r[5] = { 1.f,  0.30901699437494742f, -0.80901699437494742f,
                              -0.80901699437494742f,  0.30901699437494742f };
        const float w5i[5] = { 0.f, -0.95105651629515357f, -0.58778525229247312f,
                               0.58778525229247312f,  0.95105651629515357f };
#pragma unroll
        for (int k1 = 0; k1 < 5; k1++) {
            float ar = 0.f, ai = 0.f;
#pragma unroll
            for (int n1 = 0; n1 < 5; n1++) {
                int m = (n1 * k1) % 5;
                ar += x[n1].x * w5r[m] - x[n1].y * w5i[m];
                ai += x[n1].x * w5i[m] + x[n1].y * w5r[m];
            }
            if (k1 == 0) {
                bufB[swz(tid)] = make_float2(ar, ai);
            } else {
                float2 w = tw[k1 - 1];
                bufB[swz(k1 * 512 + tid)] =
                    make_float2(ar * w.x - ai * w.y, ar * w.y + ai * w.x);
            }
        }
    }
    __syncthreads();    // publish radix-5 writes; also fences prev-col bufA reads
    radix4_stage<0, NT>(bufB, bufA, w512x, tid); __syncthreads();
    radix4_stage<2, NT>(bufA, bufB, w512x, tid); __syncthreads();
    radix4_stage<4, NT>(bufB, bufA, w512x, tid); __syncthreads();
    radix4_stage<6, NT>(bufA, bufB, w512x, tid); __syncthreads();
    // final radix-2 (s=256, twiddle = 1)
    for (int t = tid; t < 1280; t += NT) {
        int sub = t >> 8, q = t & 255;
        int base = sub << 9;
        float2 a = bufB[swz(base + q)];
        float2 b = bufB[swz(base + q + 256)];
        bufA[swz(base + q)]       = make_float2(a.x + b.x, a.y + b.y);
        bufA[swz(base + q + 256)] = make_float2(a.x - b.x, a.y - b.y);
    }
    __syncthreads();    // publish bufA before epilogue reads; fences bufB reuse
}

// one workgroup (512 threads) per (DGRP-channel group, b)
__global__ __launch_bounds__(FFT_NT) void fft_fwd_kernel(
    const float* __restrict__ qt, const float* __restrict__ kt, float* __restrict__ Z)
{
    __shared__ float2 bufA[SEQ];
    __shared__ float2 bufB[SEQ];
    __shared__ float2 w512x[512];
    int d0 = blockIdx.x * DGRP;
    int b = blockIdx.y;
    int tid = threadIdx.x;
    {
        float sn, cs;
        sincosf(-6.283185307179586f * (float)tid / 512.0f, &sn, &cs);
        w512x[tid] = make_float2(cs, sn);
    }
    // radix-5 twiddles depend only on (k1, n2=tid): hoist to registers, once.
    float2 tw[4];
#pragma unroll
    for (int k1 = 1; k1 <= 4; k1++) {
        float sn, cs;
        sincosf(-2.4543692606170259e-3f * (float)(k1 * tid), &sn, &cs);
        tw[k1 - 1] = make_float2(cs, sn);
    }
    float accR[5], accI[5];
#pragma unroll
    for (int j = 0; j < 5; j++) { accR[j] = 0.f; accI[j] = 0.f; }

    for (int col = 0; col < DGRP; col++) {
        const float* qcol = qt + (size_t)(d0 + col) * MROWS + (size_t)b * SEQ;
        const float* kcol = kt + (size_t)(d0 + col) * MROWS + (size_t)b * SEQ;
        // direct register load (same elements the radix-5 stage consumes)
        float2 x[5];
#pragma unroll
        for (int m = 0; m < 5; m++)
            x[m] = make_float2(qcol[m * 512 + tid], kcol[m * 512 + tid]);
        fft2560<FFT_NT>(x, bufA, bufB, w512x, tw, tid);
#pragma unroll
        for (int j = 0; j < 5; j++) {
            int f = tid + FFT_NT * j;
            int fpos = (f % 5) * 512 + (f / 5);
            int g = f ? (SEQ - f) : 0;
            int gpos = (g % 5) * 512 + (g / 5);
            float2 Z1 = bufA[swz(fpos)], Z2 = bufA[swz(gpos)];
            accR[j] += 0.5f * (Z1.x * Z2.y + Z1.y * Z2.x);            // Im(Z1*Z2)/2
            accI[j] += 0.25f * ((Z1.x * Z1.x + Z1.y * Z1.y)
                              - (Z2.x * Z2.x + Z2.y * Z2.y));         // (|Z1|^2-|Z2|^2)/4
        }
    }
#pragma unroll
    for (int j = 0; j < 5; j++) {
        int f = tid + FFT_NT * j;
        int fpos = (f % 5) * 512 + (f / 5);
        atomicAdd(&Z[((size_t)b * SEQ + fpos) * 2 + 0], accR[j]);
        atomicAdd(&Z[((size_t)b * SEQ + fpos) * 2 + 1], accI[j]);
    }
}

__global__ __launch_bounds__(FFT_NT) void fft_inv_kernel(
    const float* __restrict__ Z, float* __restrict__ mc)
{
    __shared__ float2 bufA[SEQ];
    __shared__ float2 bufB[SEQ];
    __shared__ float2 w512x[512];
    int b = blockIdx.x;
    int tid = threadIdx.x;
    {
        float sn, cs;
        sincosf(-6.283185307179586f * (float)tid / 512.0f, &sn, &cs);
        w512x[tid] = make_float2(cs, sn);
    }
    float2 tw[4];
#pragma unroll
    for (int k1 = 1; k1 <= 4; k1++) {
        float sn, cs;
        sincosf(-2.4543692606170259e-3f * (float)(k1 * tid), &sn, &cs);
        tw[k1 - 1] = make_float2(cs, sn);
    }
    // direct register load with the same index map the loader used
    float2 x[5];
#pragma unroll
    for (int m = 0; m < 5; m++) {
        int i = m * 512 + tid;
        int k1 = i % 5, k2 = i / 5;
        float zr = Z[((size_t)b * SEQ + k1 * 512 + k2) * 2 + 0];
        float zi = Z[((size_t)b * SEQ + k1 * 512 + k2) * 2 + 1];
        x[m] = make_float2(zr, -zi);
    }
    fft2560<FFT_NT>(x, bufA, bufB, w512x, tw, tid);
    const float scale = 1.0f / (2560.0f * 512.0f);
    for (int j = tid; j < SEQ; j += FFT_NT) {
        int k1 = j >> 9, k2 = j & 511;
        mc[(size_t)b * SEQ + k1 + 5 * k2] = bufA[swz(j)].x * scale;
    }
}

// ---------------- top-7 + softmax per batch ----------------
__global__ __launch_bounds__(256) void topk_kernel(
    const float* __restrict__ mc, float* __restrict__ wts, int* __restrict__ dels)
{
    __shared__ float cv[SEQ];
    __shared__ float rv[256];
    __shared__ int   ri[256];
    __shared__ float topv[TOPK];
    __shared__ int   topi[TOPK];
    int b = blockIdx.x, tid = threadIdx.x;
    for (int i = tid; i < SEQ; i += 256) cv[i] = mc[(size_t)b * SEQ + i];
    __syncthreads();
    for (int it = 0; it < TOPK; it++) {
        float bv = -2e30f; int bi = 1 << 30;
        for (int i = tid; i < SEQ; i += 256) {
            float v = cv[i];
            if (v > bv || (v == bv && i < bi)) { bv = v; bi = i; }
        }
        rv[tid] = bv; ri[tid] = bi;
        __syncthreads();
        for (int off = 128; off > 0; off >>= 1) {
            if (tid < off) {
                float v2 = rv[tid + off]; int i2 = ri[tid + off];
                if (v2 > rv[tid] || (v2 == rv[tid] && i2 < ri[tid])) {
                    rv[tid] = v2; ri[tid] = i2;
                }
            }
            __syncthreads();
        }
        if (tid == 0) { topv[it] = rv[0]; topi[it] = ri[0]; cv[ri[0]] = -1e30f; }
        __syncthreads();
    }
    if (tid == 0) {
        float mx = topv[0];
        float e[TOPK], ssum = 0.f;
        for (int i = 0; i < TOPK; i++) { e[i] = expf(topv[i] - mx); ssum += e[i]; }
        for (int i = 0; i < TOPK; i++) {
            wts[b * TOPK + i] = e[i] / ssum;
            dels[b * TOPK + i] = topi[i];
        }
    }
}

// ------- fused delay aggregation + bias + residual (float4 vectorized) -------
__global__ void agg_res_kernel(const float* __restrict__ u, const float* __restrict__ x,
                               const float* __restrict__ cb,
                               const float* __restrict__ wts, const int* __restrict__ dels,
                               float* __restrict__ x1) {
    size_t i4 = ((size_t)blockIdx.x * 256 + threadIdx.x) * 4;
    if (i4 >= SD) return;
    int d = (int)(i4 & (DMODEL - 1));
    size_t r = i4 >> 9;
    int s = (int)(r % SEQ);
    int b = (int)(r / SEQ);
    float4 xx = *(const float4*)(x + i4);
    float4 cc = *(const float4*)(cb + d);
    float a0 = cc.x + xx.x, a1 = cc.y + xx.y, a2 = cc.z + xx.z, a3 = cc.w + xx.w;
    const float* ub = u + (size_t)b * SEQ * DMODEL + d;
#pragma unroll
    for (int i = 0; i < TOPK; i++) {
        int del = dels[b * TOPK + i];
        float w = wts[b * TOPK + i];
        int ss = s + del; if (ss >= SEQ) ss -= SEQ;
        float4 uu = *(const float4*)(ub + (size_t)ss * DMODEL);
        a0 += w * uu.x; a1 += w * uu.y; a2 += w * uu.z; a3 += w * uu.w;
    }
    *(float4*)(x1 + i4) = make_float4(a0, a1, a2, a3);
}

// --------- x - moving_avg(x): running-window (r5/r7 proven scalar form) ------
// TLP-fed: 640 blocks x 256 threads; serial window update per thread.
#define MA_MODE_PLAIN 0
#define MA_MODE_BF    1
#define MA_MODE_SPLIT 2
template<int MODE>
__device__ __forceinline__ void ma_run_body(
    const float* __restrict__ x, float* __restrict__ out,
    unsigned short* __restrict__ o1, unsigned short* __restrict__ o2)
{
    int tid = threadIdx.x;
    int s0 = blockIdx.x * 128;
    int d  = blockIdx.y * 256 + tid;
    int b  = blockIdx.z;
    const float* xb = x + (size_t)b * SEQ * DMODEL + d;
    float sum = 0.f;
#pragma unroll
    for (int j = -12; j <= 12; j++) {
        int ss = s0 + j;
        ss = ss < 0 ? 0 : (ss > SEQ - 1 ? SEQ - 1 : ss);
        sum += xb[(size_t)ss * DMODEL];
    }
    for (int s = s0; s < s0 + 128; s++) {
        float v = xb[(size_t)s * DMODEL] - sum * (1.0f / 25.0f);
        size_t o = ((size_t)b * SEQ + s) * DMODEL + d;
        out[o] = v;
        if (MODE == MA_MODE_BF) {
            o1[o] = f2bf(v);
        } else if (MODE == MA_MODE_SPLIT) {
            unsigned short h = f2bf(v);
            o1[o] = h;
            o2[o] = f2bf(v - bf2f(h));
        }
        int add = s + 13; if (add > SEQ - 1) add = SEQ - 1;
        int sub = s - 12; if (sub < 0) sub = 0;
        sum += xb[(size_t)add * DMODEL] - xb[(size_t)sub * DMODEL];
    }
}
__global__ __launch_bounds__(256) void ma_sub_kernel(
    const float* __restrict__ x, float* __restrict__ out) {
    ma_run_body<MA_MODE_PLAIN>(x, out, nullptr, nullptr);
}
__global__ __launch_bounds__(256) void ma_sub_bf_kernel(
    const float* __restrict__ x, float* __restrict__ out,
    unsigned short* __restrict__ obf) {
    ma_run_body<MA_MODE_BF>(x, out, obf, nullptr);
}
__global__ __launch_bounds__(256) void ma_sub_split_kernel(
    const float* __restrict__ x, float* __restrict__ out,
    unsigned short* __restrict__ hi, unsigned short* __restrict__ lo) {
    ma_run_body<MA_MODE_SPLIT>(x, out, hi, lo);
}

// ---------------- layernorm over last dim ----------------
__global__ __launch_bounds__(256) void ln_kernel(
    const float* __restrict__ x, const float* __restrict__ g,
    const float* __restrict__ be, float* __restrict__ xh)
{
    int row = blockIdx.x;
    int tid = threadIdx.x;
    __shared__ float red[256];
    const float* xr = x + (size_t)row * DMODEL;
    float v0 = xr[tid], v1 = xr[tid + 256];
    red[tid] = v0 + v1;
    __syncthreads();
    for (int off = 128; off > 0; off >>= 1) {
        if (tid < off) red[tid] += red[tid + off];
        __syncthreads();
    }
    float mu = red[0] / (float)DMODEL;
    __syncthreads();
    float d0 = v0 - mu, d1 = v1 - mu;
    red[tid] = d0 * d0 + d1 * d1;
    __syncthreads();
    for (int off = 128; off > 0; off >>= 1) {
        if (tid < off) red[tid] += red[tid + off];
        __syncthreads();
    }
    float inv = rsqrtf(red[0] / (float)DMODEL + 1e-5f);
    xh[(size_t)row * DMODEL + tid]       = d0 * inv * g[tid] + be[tid];
    xh[(size_t)row * DMODEL + tid + 256] = d1 * inv * g[tid + 256] + be[tid + 256];
}

// ------ per-(b,d) mean over sequence (float4 cols, atomic partials) ----------
__global__ __launch_bounds__(256) void colmean_kernel(
    const float* __restrict__ xh, float* __restrict__ cm) {
    int q = blockIdx.x * 256 + threadIdx.x;     // 0..2047, 4 cols each
    int idx = q * 4;                            // (b,d) base
    int d = idx & (DMODEL - 1), b = idx >> 9;
    int s0 = blockIdx.y * 128;
    const float* xb = xh + (size_t)b * SEQ * DMODEL + d;
    float a0 = 0.f, a1 = 0.f, a2 = 0.f, a3 = 0.f;
    for (int s = s0; s < s0 + 128; s++) {
        float4 v = *(const float4*)(xb + (size_t)s * DMODEL);
        a0 += v.x; a1 += v.y; a2 += v.z; a3 += v.w;
    }
    atomicAdd(&cm[idx + 0], a0 * (1.0f / (float)SEQ));
    atomicAdd(&cm[idx + 1], a1 * (1.0f / (float)SEQ));
    atomicAdd(&cm[idx + 2], a2 * (1.0f / (float)SEQ));
    atomicAdd(&cm[idx + 3], a3 * (1.0f / (float)SEQ));
}

__global__ __launch_bounds__(256) void final_kernel(
    const float* __restrict__ xh, const float* __restrict__ cm,
    const float* __restrict__ Wp, const float* __restrict__ bp,
    float* __restrict__ out)
{
    int b = blockIdx.y, chunk = blockIdx.x;
    int tid = threadIdx.x;
    const size_t per = (size_t)SEQ * DMODEL / 64;   // 20480, %1024 == 0
    size_t start = (size_t)chunk * per;
    float acc = 0.f;
    for (size_t i = start + tid * 4; i < start + per; i += 1024) {
        int d = (int)(i & (DMODEL - 1));
        float4 v = *(const float4*)(xh + (size_t)b * SEQ * DMODEL + i);
        float4 c = *(const float4*)(cm + b * DMODEL + d);
        float4 w = *(const float4*)(Wp + i);
        acc += gelu_f(v.x - c.x) * w.x + gelu_f(v.y - c.y) * w.y
             + gelu_f(v.z - c.z) * w.z + gelu_f(v.w - c.w) * w.w;
    }
    __shared__ float red[256];
    red[tid] = acc;
    __syncthreads();
    for (int off = 128; off > 0; off >>= 1) {
        if (tid < off) red[tid] += red[tid + off];
        __syncthreads();
    }
    if (tid == 0) {
        atomicAdd(&out[b], red[0]);
        if (chunk == 0) atomicAdd(&out[b], bp[0]);
    }
}

// ---------------- orchestration: 3-buffer rotation, NO input/output aliasing ----
extern "C" void kernel_launch(void* const* d_in, const int* in_sizes, int n_in,
                              void* d_out, int out_size, void* d_ws, size_t ws_size,
                              hipStream_t stream) {
    const float* data  = (const float*)d_in[0];
    const float* mask  = (const float*)d_in[1];
    const float* Wemb  = (const float*)d_in[2];
    const float* Wq    = (const float*)d_in[3];
    const float* bq    = (const float*)d_in[4];
    const float* Wk    = (const float*)d_in[5];
    const float* bk    = (const float*)d_in[6];
    const float* Wv    = (const float*)d_in[7];
    const float* bv    = (const float*)d_in[8];
    const float* Wo    = (const float*)d_in[9];
    const float* bo    = (const float*)d_in[10];
    const float* Wc1   = (const float*)d_in[11];
    const float* Wc2   = (const float*)d_in[12];
    const float* gamma = (const float*)d_in[13];
    const float* beta  = (const float*)d_in[14];
    const float* Wp    = (const float*)d_in[15];
    const float* bp    = (const float*)d_in[16];
    float* out = (float*)d_out;

    float* buf0 = (float*)d_ws;
    float* buf1 = buf0 + SD;
    float* buf2 = buf1 + SD;

    unsigned short* WstkH = (unsigned short*)(buf2 + SD);   // 2*512*512 stacked q/k hi
    unsigned short* WstkL = WstkH + 2 * DMODEL * DMODEL;    // stacked q/k lo
    unsigned short* Wvot  = WstkL + 2 * DMODEL * DMODEL;    // bf16 [N][K] of Wv@Wo
    unsigned short* Wc1t  = Wvot + DMODEL * DMODEL;         // [2048][512]
    unsigned short* Wc2t  = Wc1t + (size_t)DMODEL * DFF;    // [512][2048]
    float* WvoF = (float*)(Wc2t + (size_t)DMODEL * DFF);    // fp32 Wv@Wo (512x512)
    float* CB   = WvoF + (size_t)DMODEL * DMODEL;           // cb = bv@Wo + bo
    float* Bstk = CB + DMODEL;                              // stacked q/k bias (1024)
    float* Zb = Bstk + 1024;
    float* MC = Zb + (size_t)BATCH * SEQ * 2;
    float* WT = MC + (size_t)BATCH * SEQ;
    int*   DL = (int*)(WT + BATCH * TOPK);
    float* CM = (float*)(DL + BATCH * TOPK);

    const int NB  = (int)((SD + 255) / 256);
    const int NB4 = (int)((SD / 4 + 255) / 256);
    dim3 gMA(SEQ / 128, 2, BATCH);              // (20, 2, 16) running-window MA

    float* X  = buf0;   // x fp32
    float* HL = buf1;   // hi/lo pool
    float* S  = buf2;   // scratch

    // embed + fused hi/lo split (vectorized): hi -> upper half of HL, lo -> lower
    embed_kernel<<<MROWS / 2, 256, 0, stream>>>(data, mask, Wemb, X,
                                                (unsigned short*)HL + SD,
                                                (unsigned short*)HL);

    // 1-D swizzled GEMM grids: blocks = gridM*gridN (gridM % 8 == 0)
    const int gSqBlocks = (MROWS / 128) * (DMODEL / 128);       // 320*4 = 1280
    const int gF1Blocks = (FFN_CHUNK / 128) * (DFF / 128);      // 160*16 = 2560
    const int gF2Blocks = (FFN_CHUNK / 128) * (DMODEL / 128);   // 160*4 = 640

    for (int l = 0; l < NLAYERS; l++) {
        const float* wq = Wq + (size_t)l * DMODEL * DMODEL;
        const float* wk = Wk + (size_t)l * DMODEL * DMODEL;
        const float* wv = Wv + (size_t)l * DMODEL * DMODEL;
        const float* wo = Wo + (size_t)l * DMODEL * DMODEL;
        const float* bqL = bq + (size_t)l * DMODEL;
        const float* bkL = bk + (size_t)l * DMODEL;
        const float* bvL = bv + (size_t)l * DMODEL;
        const float* boL = bo + (size_t)l * DMODEL;
        const float* wc1 = Wc1 + (size_t)l * DMODEL * DFF;
        const float* wc2 = Wc2 + (size_t)l * DFF * DMODEL;

        unsigned short* Lbf = (unsigned short*)HL;      // x_lo (lower half)
        unsigned short* Hbf = Lbf + SD;                 // x_hi (upper half)
        float* qtf = S;                                 // q cols (MROWS*256)
        float* ktf = S + (size_t)MROWS * CHUNK_D;       // k cols

        dim3 gT(DMODEL / 32, DMODEL / 32);
        transpose_split_stk_kernel<<<gT, 256, 0, stream>>>(wq, WstkH, WstkL, 0);
        transpose_split_stk_kernel<<<gT, 256, 0, stream>>>(wk, WstkH, WstkL, 1);
        stack_bias_kernel<<<4, 256, 0, stream>>>(bqL, bkL, Bstk);
        wvo_kernel<<<DMODEL, 256, 0, stream>>>(wv, wo, WvoF);
        transpose_bf16_kernel<<<gT, 256, 0, stream>>>(WvoF, Wvot, DMODEL, DMODEL);
        cbias_kernel<<<2, 256, 0, stream>>>(bvL, wo, boL, CB);
        transpose_bf16_kernel<<<dim3(DFF / 32, DMODEL / 32), 256, 0, stream>>>(wc1, Wc1t, DMODEL, DFF);
        transpose_bf16_kernel<<<dim3(DMODEL / 32, DFF / 32), 256, 0, stream>>>(wc2, Wc2t, DFF, DMODEL);

        // q&k stacked: one split GEMM per 256-col chunk into S (N=512 covers both)
        hipMemsetAsync(Zb, 0, (size_t)BATCH * SEQ * 2 * sizeof(float), stream);
        for (int c = 0; c < DMODEL / CHUNK_D; c++) {
            gemm_qk_split_kernel<<<gSqBlocks, 256, 0, stream>>>(
                Hbf, Lbf, WstkH + (size_t)c * 512 * DMODEL,
                WstkL + (size_t)c * 512 * DMODEL, Bstk + c * 512,
                S, MROWS, DMODEL, DMODEL / 128);
            fft_fwd_kernel<<<dim3(CHUNK_D / DGRP, BATCH), FFT_NT, 0, stream>>>(qtf, ktf, Zb);
        }
        fft_inv_kernel<<<BATCH, FFT_NT, 0, stream>>>(Zb, MC);
        topk_kernel<<<BATCH, 256, 0, stream>>>(MC, WT, DL);

        // u = x@(Wv@Wo) -> S fp32 (qtf/ktf dead)
        gemm_mfma_kernel<<<gSqBlocks, 256, 0, stream>>>(Hbf, Wvot, nullptr, nullptr, S,
                                                        MROWS, DMODEL, DMODEL, 0, 0,
                                                        DMODEL / 128);
        // x1 = sum w_i roll(u) + cb + x -> HL as fp32 (x hi/lo dead)
        agg_res_kernel<<<NB4, 256, 0, stream>>>(S, X, CB, WT, DL, HL);
        // x2 = x1 - MA(x1): fp32 -> X (x dead), bf16 -> S (u dead). No aliasing.
        ma_sub_bf_kernel<<<gMA, 256, 0, stream>>>(HL, X, (unsigned short*)S);
        // FFN in 2 row-chunks: gelu bf16 fills HL exactly (x1 dead);
        // z in-place over X (res==out, same-index).
        for (int c = 0; c < MROWS / FFN_CHUNK; c++) {
            const unsigned short* x2c = (unsigned short*)S + (size_t)c * FFN_CHUNK * DMODEL;
            float* xz = X + (size_t)c * FFN_CHUNK * DMODEL;
            gemm_mfma_kernel<<<gF1Blocks, 256, 0, stream>>>(x2c, Wc1t, nullptr, nullptr,
                                                            (unsigned short*)HL,
                                                            FFN_CHUNK, DFF, DMODEL, 1, 1,
                                                            DFF / 128);
            gemm_mfma_kernel<<<gF2Blocks, 256, 0, stream>>>((unsigned short*)HL, Wc2t,
                                                            nullptr, xz, xz,
                                                            FFN_CHUNK, DMODEL, DFF, 0, 0,
                                                            DMODEL / 128);
        }
        // h = z - MA(z): z in X -> h fp32 -> S (+ hi/lo -> HL if another layer)
        if (l + 1 < NLAYERS)
            ma_sub_split_kernel<<<gMA, 256, 0, stream>>>(
                X, S, (unsigned short*)HL + SD, (unsigned short*)HL);
        else
            ma_sub_kernel<<<gMA, 256, 0, stream>>>(X, S);
        // rotate: next layer's x is in S
        float* tmp = X; X = S; S = tmp;
    }

    // final h is in X; use HL for xh
    ln_kernel<<<MROWS, 256, 0, stream>>>(X, gamma, beta, HL);
    hipMemsetAsync(CM, 0, (size_t)BATCH * DMODEL * sizeof(float), stream);
    colmean_kernel<<<dim3(8, 20), 256, 0, stream>>>(HL, CM);
    hipMemsetAsync(out, 0, (size_t)out_size * sizeof(float), stream);
    final_kernel<<<dim3(64, BATCH), 256, 0, stream>>>(HL, CM, Wp, bp, out);
}